// Round 1
// baseline (4689.057 us; speedup 1.0000x reference)
//
#include <hip/hip_runtime.h>
#include <hip/hip_bf16.h>
#include <stdint.h>

typedef __attribute__((ext_vector_type(8))) short bf16x8;
typedef __attribute__((ext_vector_type(4))) float f32x4;
typedef unsigned short u16;

__device__ inline float bf2f(u16 u) {
  unsigned int x = ((unsigned int)u) << 16;
  return __builtin_bit_cast(float, x);
}
__device__ inline u16 f2bf(float f) {
  unsigned int x = __builtin_bit_cast(unsigned int, f);
  unsigned int r = x + 0x7fffu + ((x >> 16) & 1u);
  return (u16)(r >> 16);
}

__device__ inline void load_lds16(const void* g, void* l) {
  __builtin_amdgcn_global_load_lds(
      (const __attribute__((address_space(1))) unsigned int*)g,
      (__attribute__((address_space(3))) unsigned int*)l, 16, 0, 0);
}

// ---------------- embedding + positional encoding ----------------
__global__ __launch_bounds__(256) void embed_kernel(
    const int* __restrict__ x, const float* __restrict__ emb,
    float* __restrict__ h) {
  const int row = blockIdx.x;          // b*1024 + s
  const int s = row & 1023;
  const int tok = x[row];
  const int tid = threadIdx.x;
  const float c = -logf(10000.f) / 768.f;
#pragma unroll
  for (int i = 0; i < 3; ++i) {
    const int d = tid + i * 256;
    const int deven = d & ~1;
    const float ang = (float)s * expf((float)deven * c);
    const float pe = (d & 1) ? cosf(ang) : sinf(ang);
    h[(long)row * 768 + d] = emb[(long)tok * 768 + d] * 27.712812921102035f + pe;
  }
}

// ---------------- layernorm (f32 in -> bf16 out) ----------------
__global__ __launch_bounds__(256) void ln_kernel(
    const float* __restrict__ X, const float* __restrict__ g,
    const float* __restrict__ b, u16* __restrict__ Y) {
  const int row = blockIdx.x;
  const float* xr = X + (long)row * 768;
  const int tid = threadIdx.x;
  float v[3];
  float s = 0.f, sq = 0.f;
#pragma unroll
  for (int i = 0; i < 3; ++i) {
    v[i] = xr[tid + i * 256];
    s += v[i];
    sq += v[i] * v[i];
  }
  __shared__ float red[8];
#pragma unroll
  for (int off = 32; off > 0; off >>= 1) {
    s += __shfl_down(s, off);
    sq += __shfl_down(sq, off);
  }
  const int lane = tid & 63, wid = tid >> 6;
  if (lane == 0) { red[wid] = s; red[wid + 4] = sq; }
  __syncthreads();
  s = red[0] + red[1] + red[2] + red[3];
  sq = red[4] + red[5] + red[6] + red[7];
  const float mean = s * (1.f / 768.f);
  const float var = sq * (1.f / 768.f) - mean * mean;
  const float rs = rsqrtf(var + 1e-5f);
  u16* yr = Y + (long)row * 768;
#pragma unroll
  for (int i = 0; i < 3; ++i) {
    const int d = tid + i * 256;
    yr[d] = f2bf((v[i] - mean) * rs * g[d] + b[d]);
  }
}

// ---------------- f32 (K x N) -> bf16 transposed (Npad x K) ----------------
__global__ void conv_transpose(const float* __restrict__ W, u16* __restrict__ Wt,
                               int K, int N, int Npad) {
  __shared__ float tile[32][33];
  const int n0 = blockIdx.x * 32, k0 = blockIdx.y * 32;
  const int tx = threadIdx.x, ty = threadIdx.y;
  for (int i = ty; i < 32; i += 8) {
    const int n = n0 + tx;
    tile[i][tx] = (n < N) ? W[(long)(k0 + i) * N + n] : 0.f;
  }
  __syncthreads();
  for (int i = ty; i < 32; i += 8) {
    const int n = n0 + i;
    if (n < Npad) Wt[(long)n * K + k0 + tx] = f2bf(tile[tx][i]);
  }
}

// ---------------- bf16 (R x C) -> (C x R), batched in z ----------------
__global__ void transpose_bf16_k(const u16* __restrict__ in, u16* __restrict__ out,
                                 int R, int C) {
  __shared__ u16 tile[32][33];
  const long boff = (long)blockIdx.z * R * C;
  const int c0 = blockIdx.x * 32, r0 = blockIdx.y * 32;
  const int tx = threadIdx.x, ty = threadIdx.y;
  for (int i = ty; i < 32; i += 8)
    tile[i][tx] = in[boff + (long)(r0 + i) * C + c0 + tx];
  __syncthreads();
  for (int i = ty; i < 32; i += 8)
    out[boff + (long)(c0 + i) * R + r0 + tx] = tile[tx][i];
}

// ---------------- masked softmax over rows of 1024 (f32 -> bf16 P) ----------------
__global__ __launch_bounds__(256) void softmax_kernel(
    const float* __restrict__ Sc, u16* __restrict__ P) {
  const long rb = (long)blockIdx.x * 1024;
  const int i = blockIdx.x & 1023;    // query index
  const int tid = threadIdx.x;
  const float4 sv = ((const float4*)(Sc + rb))[tid];
  float sl[4];
  const int j0 = tid * 4;
  sl[0] = (j0 + 0 <= i) ? -1e9f : sv.x;
  sl[1] = (j0 + 1 <= i) ? -1e9f : sv.y;
  sl[2] = (j0 + 2 <= i) ? -1e9f : sv.z;
  sl[3] = (j0 + 3 <= i) ? -1e9f : sv.w;
  float mx = fmaxf(fmaxf(sl[0], sl[1]), fmaxf(sl[2], sl[3]));
  __shared__ float red[4];
#pragma unroll
  for (int off = 32; off > 0; off >>= 1) mx = fmaxf(mx, __shfl_down(mx, off));
  const int lane = tid & 63, wid = tid >> 6;
  if (lane == 0) red[wid] = mx;
  __syncthreads();
  mx = fmaxf(fmaxf(red[0], red[1]), fmaxf(red[2], red[3]));
  float p[4], sum = 0.f;
#pragma unroll
  for (int c = 0; c < 4; ++c) { p[c] = __expf(sl[c] - mx); sum += p[c]; }
  __syncthreads();
#pragma unroll
  for (int off = 32; off > 0; off >>= 1) sum += __shfl_down(sum, off);
  if (lane == 0) red[wid] = sum;
  __syncthreads();
  sum = red[0] + red[1] + red[2] + red[3];
  const float inv = 1.f / sum;
  u16* pr = P + rb + j0;
#pragma unroll
  for (int c = 0; c < 4; ++c) pr[c] = f2bf(p[c] * inv);
}

// ---------------- generic bf16 MFMA GEMM: C = (A * Wt^T + bias)*scale (+resid)(relu) ----------------
// A: M x K (lda), Wt: N x K (ldw) i.e. row n holds K values for output col n.
// z-batched: b = z/zdiv, r = z%zdiv; offsets = b*s1 + r*s2 (elements).
template <int BM, int BN, int FM, int FN>
__global__ __launch_bounds__(256) void gemm_bf16(
    const u16* __restrict__ A, const u16* __restrict__ Wt,
    const float* __restrict__ bias, const float* resid,
    float* outF, u16* outB,
    int K, int lda, int ldw, int ldc,
    long sA1, long sA2, long sW1, long sW2, long sC1, long sC2,
    int zdiv, int Nreal, float scale, int relu) {
  __shared__ u16 As[BM * 32];
  __shared__ u16 Bs[BN * 32];

  const int z = blockIdx.z;
  const int zq = z / zdiv, zr = z % zdiv;
  A += (long)zq * sA1 + (long)zr * sA2;
  Wt += (long)zq * sW1 + (long)zr * sW2;
  const long coff = (long)zq * sC1 + (long)zr * sC2;

  const int tid = threadIdx.x;
  const int lane = tid & 63;
  const int wid = tid >> 6;
  const int wm = wid >> 1, wn = wid & 1;
  const int lrow = lane & 15, kgrp = lane >> 4;

  const long row0 = (long)blockIdx.y * BM;
  const long col0 = (long)blockIdx.x * BN;

  f32x4 acc[FM][FN];
#pragma unroll
  for (int m = 0; m < FM; ++m)
#pragma unroll
    for (int n = 0; n < FN; ++n) acc[m][n] = (f32x4){0.f, 0.f, 0.f, 0.f};

  constexpr int ACALLS = (BM * 64) / 4096;
  constexpr int BCALLS = (BN * 64) / 4096;

  for (int k0 = 0; k0 < K; k0 += 32) {
    __syncthreads();
#pragma unroll
    for (int c = 0; c < ACALLS; ++c) {
      const int o = c * 4096 + tid * 16;
      const int r = o >> 6;
      const int kb = (o & 63) >> 1;
      load_lds16(A + (row0 + r) * lda + k0 + kb, (char*)As + o);
    }
#pragma unroll
    for (int c = 0; c < BCALLS; ++c) {
      const int o = c * 4096 + tid * 16;
      const int r = o >> 6;
      const int kb = (o & 63) >> 1;
      load_lds16(Wt + (col0 + r) * ldw + k0 + kb, (char*)Bs + o);
    }
    __syncthreads();

    bf16x8 af[FM], bfr[FN];
#pragma unroll
    for (int m = 0; m < FM; ++m)
      af[m] = *(const bf16x8*)&As[(wm * FM * 16 + m * 16 + lrow) * 32 + kgrp * 8];
#pragma unroll
    for (int n = 0; n < FN; ++n)
      bfr[n] = *(const bf16x8*)&Bs[(wn * FN * 16 + n * 16 + lrow) * 32 + kgrp * 8];
#pragma unroll
    for (int m = 0; m < FM; ++m)
#pragma unroll
      for (int n = 0; n < FN; ++n)
        acc[m][n] = __builtin_amdgcn_mfma_f32_16x16x32_bf16(af[m], bfr[n], acc[m][n], 0, 0, 0);
  }

#pragma unroll
  for (int m = 0; m < FM; ++m) {
    const long row = row0 + wm * FM * 16 + m * 16 + kgrp * 4;
#pragma unroll
    for (int n = 0; n < FN; ++n) {
      const long col = col0 + wn * FN * 16 + n * 16 + lrow;
      if (col < Nreal) {
        const float bb = bias ? bias[col] : 0.f;
#pragma unroll
        for (int r = 0; r < 4; ++r) {
          const long idx = coff + (row + r) * ldc + col;
          float v = (acc[m][n][r] + bb) * scale;
          if (resid) v += resid[idx];
          if (relu) v = fmaxf(v, 0.f);
          if (outF) outF[idx] = v;
          else outB[idx] = f2bf(v);
        }
      }
    }
  }
}

extern "C" void kernel_launch(void* const* d_in, const int* in_sizes, int n_in,
                              void* d_out, int out_size, void* d_ws, size_t ws_size,
                              hipStream_t stream) {
  const int* x = (const int*)d_in[0];
  const float* tok_emb = (const float*)d_in[1];
  const float* Wq = (const float*)d_in[2];
  const float* bq = (const float*)d_in[3];
  const float* Wk = (const float*)d_in[4];
  const float* bk = (const float*)d_in[5];
  const float* Wv = (const float*)d_in[6];
  const float* bv = (const float*)d_in[7];
  const float* Wo = (const float*)d_in[8];
  const float* bo = (const float*)d_in[9];
  const float* ln1g = (const float*)d_in[10];
  const float* ln1b = (const float*)d_in[11];
  const float* ln2g = (const float*)d_in[12];
  const float* ln2b = (const float*)d_in[13];
  const float* W1 = (const float*)d_in[14];
  const float* b1 = (const float*)d_in[15];
  const float* W2 = (const float*)d_in[16];
  const float* b2 = (const float*)d_in[17];
  const float* lnfg = (const float*)d_in[18];
  const float* lnfb = (const float*)d_in[19];
  const float* Wout = (const float*)d_in[20];
  const float* bout = (const float*)d_in[21];

  char* p = (char*)d_ws;
  auto alloc = [&](size_t bytes) {
    void* r = (void*)p;
    p += (bytes + 255) & ~(size_t)255;
    return r;
  };
  float* h = (float*)alloc(2048L * 768 * 4);
  u16* y = (u16*)alloc(2048L * 768 * 2);
  u16* q_lin = (u16*)alloc(2048L * 768 * 2);
  u16* k_lin = (u16*)alloc(2048L * 768 * 2);
  u16* v_lin = (u16*)alloc(2048L * 768 * 2);
  u16* v_t = (u16*)alloc(2L * 768 * 1024 * 2);
  u16* att = (u16*)alloc(2048L * 768 * 2);
  u16* mid = (u16*)alloc(2048L * 3072 * 2);
  u16* wq_t = (u16*)alloc(768L * 768 * 2);
  u16* wk_t = (u16*)alloc(768L * 768 * 2);
  u16* wv_t = (u16*)alloc(768L * 768 * 2);
  u16* wo_t = (u16*)alloc(768L * 768 * 2);
  u16* w1_t = (u16*)alloc(768L * 3072 * 2);
  u16* w2_t = (u16*)alloc(768L * 3072 * 2);
  u16* wout_t = (u16*)alloc(50304L * 768 * 2);

  float* scores = (float*)d_out;                       // 24*1024*1024 f32 = 100663296 B
  u16* P = (u16*)((char*)d_out + 100663296);           // 24*1024*1024 bf16

  const dim3 tb(256);
  const dim3 cb(32, 8);

  embed_kernel<<<2048, tb, 0, stream>>>(x, tok_emb, h);

  // vocab weight conversion (independent of layers)
  conv_transpose<<<dim3(1572, 24), cb, 0, stream>>>(Wout, wout_t, 768, 50257, 50304);

  for (int l = 0; l < 12; ++l) {
    conv_transpose<<<dim3(24, 24), cb, 0, stream>>>(Wq + l * 589824L, wq_t, 768, 768, 768);
    conv_transpose<<<dim3(24, 24), cb, 0, stream>>>(Wk + l * 589824L, wk_t, 768, 768, 768);
    conv_transpose<<<dim3(24, 24), cb, 0, stream>>>(Wv + l * 589824L, wv_t, 768, 768, 768);
    conv_transpose<<<dim3(24, 24), cb, 0, stream>>>(Wo + l * 589824L, wo_t, 768, 768, 768);
    conv_transpose<<<dim3(96, 24), cb, 0, stream>>>(W1 + l * 2359296L, w1_t, 768, 3072, 3072);
    conv_transpose<<<dim3(24, 96), cb, 0, stream>>>(W2 + l * 2359296L, w2_t, 3072, 768, 768);

    ln_kernel<<<2048, tb, 0, stream>>>(h, ln1g + l * 768, ln1b + l * 768, y);

    // QKV projections (q scaled by 1/sqrt(64))
    gemm_bf16<128, 128, 4, 4><<<dim3(6, 16, 1), tb, 0, stream>>>(
        y, wq_t, bq + l * 768, nullptr, nullptr, q_lin,
        768, 768, 768, 768, 0, 0, 0, 0, 0, 0, 1, 768, 0.125f, 0);
    gemm_bf16<128, 128, 4, 4><<<dim3(6, 16, 1), tb, 0, stream>>>(
        y, wk_t, bk + l * 768, nullptr, nullptr, k_lin,
        768, 768, 768, 768, 0, 0, 0, 0, 0, 0, 1, 768, 1.f, 0);
    gemm_bf16<128, 128, 4, 4><<<dim3(6, 16, 1), tb, 0, stream>>>(
        y, wv_t, bv + l * 768, nullptr, nullptr, v_lin,
        768, 768, 768, 768, 0, 0, 0, 0, 0, 0, 1, 768, 1.f, 0);

    transpose_bf16_k<<<dim3(24, 32, 2), cb, 0, stream>>>(v_lin, v_t, 1024, 768);

    // scores = q @ k^T (already scaled), z = b*12 + h
    gemm_bf16<128, 128, 4, 4><<<dim3(8, 8, 24), tb, 0, stream>>>(
        q_lin, k_lin, nullptr, nullptr, scores, nullptr,
        64, 768, 768, 1024,
        786432L, 64L, 786432L, 64L, 12582912L, 1048576L, 12, 1024, 1.f, 0);

    softmax_kernel<<<24576, tb, 0, stream>>>(scores, P);

    // att = P @ V  (Wt = v_t: 64 x 1024 per head)
    gemm_bf16<128, 64, 4, 2><<<dim3(1, 8, 24), tb, 0, stream>>>(
        P, v_t, nullptr, nullptr, nullptr, att,
        1024, 1024, 1024, 768,
        12582912L, 1048576L, 786432L, 65536L, 786432L, 64L, 12, 64, 1.f, 0);

    // h += att @ Wo + bo
    gemm_bf16<128, 128, 4, 4><<<dim3(6, 16, 1), tb, 0, stream>>>(
        att, wo_t, bo + l * 768, h, h, nullptr,
        768, 768, 768, 768, 0, 0, 0, 0, 0, 0, 1, 768, 1.f, 0);

    ln_kernel<<<2048, tb, 0, stream>>>(h, ln2g + l * 768, ln2b + l * 768, y);

    // mid = relu(y @ W1 + b1)
    gemm_bf16<128, 128, 4, 4><<<dim3(24, 16, 1), tb, 0, stream>>>(
        y, w1_t, b1 + l * 3072, nullptr, nullptr, mid,
        768, 768, 768, 3072, 0, 0, 0, 0, 0, 0, 1, 3072, 1.f, 1);

    // h += mid @ W2 + b2
    gemm_bf16<128, 128, 4, 4><<<dim3(6, 16, 1), tb, 0, stream>>>(
        mid, w2_t, b2 + l * 768, h, h, nullptr,
        3072, 3072, 3072, 768, 0, 0, 0, 0, 0, 0, 1, 768, 1.f, 0);
  }

  ln_kernel<<<2048, tb, 0, stream>>>(h, lnfg, lnfb, y);

  // logits = y @ Wout + bout
  gemm_bf16<128, 128, 4, 4><<<dim3(393, 16, 1), tb, 0, stream>>>(
      y, wout_t, bout, nullptr, (float*)d_out, nullptr,
      768, 768, 768, 50257, 0, 0, 0, 0, 0, 0, 1, 50257, 1.f, 0);
}

// Round 2
// 3012.585 us; speedup vs baseline: 1.5565x; 1.5565x over previous
//
#include <hip/hip_runtime.h>
#include <hip/hip_bf16.h>
#include <stdint.h>

typedef __attribute__((ext_vector_type(8))) short bf16x8;
typedef __attribute__((ext_vector_type(4))) float f32x4;
typedef unsigned short u16;

__device__ inline float bf2f(u16 u) {
  unsigned int x = ((unsigned int)u) << 16;
  return __builtin_bit_cast(float, x);
}
__device__ inline u16 f2bf(float f) {
  unsigned int x = __builtin_bit_cast(unsigned int, f);
  unsigned int r = x + 0x7fffu + ((x >> 16) & 1u);
  return (u16)(r >> 16);
}

__device__ inline void load_lds16(const void* g, void* l) {
  __builtin_amdgcn_global_load_lds(
      (const __attribute__((address_space(1))) unsigned int*)g,
      (__attribute__((address_space(3))) unsigned int*)l, 16, 0, 0);
}

// ---------------- embedding + positional encoding ----------------
__global__ __launch_bounds__(256) void embed_kernel(
    const int* __restrict__ x, const float* __restrict__ emb,
    float* __restrict__ h) {
  const int row = blockIdx.x;          // b*1024 + s
  const int s = row & 1023;
  const int tok = x[row];
  const int tid = threadIdx.x;
  const float c = -logf(10000.f) / 768.f;
#pragma unroll
  for (int i = 0; i < 3; ++i) {
    const int d = tid + i * 256;
    const int deven = d & ~1;
    const float ang = (float)s * expf((float)deven * c);
    const float pe = (d & 1) ? cosf(ang) : sinf(ang);
    h[(long)row * 768 + d] = emb[(long)tok * 768 + d] * 27.712812921102035f + pe;
  }
}

// ---------------- layernorm (f32 in -> bf16 out) ----------------
__global__ __launch_bounds__(256) void ln_kernel(
    const float* __restrict__ X, const float* __restrict__ g,
    const float* __restrict__ b, u16* __restrict__ Y) {
  const int row = blockIdx.x;
  const float* xr = X + (long)row * 768;
  const int tid = threadIdx.x;
  float v[3];
  float s = 0.f, sq = 0.f;
#pragma unroll
  for (int i = 0; i < 3; ++i) {
    v[i] = xr[tid + i * 256];
    s += v[i];
    sq += v[i] * v[i];
  }
  __shared__ float red[8];
#pragma unroll
  for (int off = 32; off > 0; off >>= 1) {
    s += __shfl_down(s, off);
    sq += __shfl_down(sq, off);
  }
  const int lane = tid & 63, wid = tid >> 6;
  if (lane == 0) { red[wid] = s; red[wid + 4] = sq; }
  __syncthreads();
  s = red[0] + red[1] + red[2] + red[3];
  sq = red[4] + red[5] + red[6] + red[7];
  const float mean = s * (1.f / 768.f);
  const float var = sq * (1.f / 768.f) - mean * mean;
  const float rs = rsqrtf(var + 1e-5f);
  u16* yr = Y + (long)row * 768;
#pragma unroll
  for (int i = 0; i < 3; ++i) {
    const int d = tid + i * 256;
    yr[d] = f2bf((v[i] - mean) * rs * g[d] + b[d]);
  }
}

// ---------------- f32 (K x N) -> bf16 transposed (Npad x K) ----------------
__global__ void conv_transpose(const float* __restrict__ W, u16* __restrict__ Wt,
                               int K, int N, int Npad) {
  __shared__ float tile[32][33];
  const int n0 = blockIdx.x * 32, k0 = blockIdx.y * 32;
  const int tx = threadIdx.x, ty = threadIdx.y;
  for (int i = ty; i < 32; i += 8) {
    const int n = n0 + tx;
    tile[i][tx] = (n < N) ? W[(long)(k0 + i) * N + n] : 0.f;
  }
  __syncthreads();
  for (int i = ty; i < 32; i += 8) {
    const int n = n0 + i;
    if (n < Npad) Wt[(long)n * K + k0 + tx] = f2bf(tile[tx][i]);
  }
}

// ---- merged Wq/Wk/Wv/Wo conversion (all 768x768), z = which ----
__global__ void conv_qkvo(const float* __restrict__ Wq, const float* __restrict__ Wk,
                          const float* __restrict__ Wv, const float* __restrict__ Wo,
                          u16* __restrict__ qkv_t, u16* __restrict__ wo_t) {
  __shared__ float tile[32][33];
  const int z = blockIdx.z;
  const float* W = (z == 0) ? Wq : (z == 1) ? Wk : (z == 2) ? Wv : Wo;
  u16* dst = (z < 3) ? qkv_t + (long)z * 768 * 768 : wo_t;
  const int n0 = blockIdx.x * 32, k0 = blockIdx.y * 32;
  const int tx = threadIdx.x, ty = threadIdx.y;
  for (int i = ty; i < 32; i += 8)
    tile[i][tx] = W[(long)(k0 + i) * 768 + n0 + tx];
  __syncthreads();
  for (int i = ty; i < 32; i += 8)
    dst[(long)(n0 + i) * 768 + k0 + tx] = f2bf(tile[tx][i]);
}

// ---- bias concat: bqkv = [bq, bk, bv] ----
__global__ void concat3(const float* __restrict__ a, const float* __restrict__ b,
                        const float* __restrict__ c, float* __restrict__ o) {
  const int i = blockIdx.x * 256 + threadIdx.x;
  if (i < 2304)
    o[i] = (i < 768) ? a[i] : (i < 1536) ? b[i - 768] : c[i - 1536];
}

// ---- v segment of qkv [2048][2304] -> v_t [2][768][1024] ----
__global__ void transpose_v(const u16* __restrict__ qkv, u16* __restrict__ v_t) {
  __shared__ u16 tile[32][33];
  const int b = blockIdx.z;
  const int c0 = blockIdx.x * 32;   // over 768 v-cols
  const int r0 = blockIdx.y * 32;   // over 1024 seq
  const int tx = threadIdx.x, ty = threadIdx.y;
  const u16* in = qkv + (long)b * 1024 * 2304 + 1536;
  for (int i = ty; i < 32; i += 8)
    tile[i][tx] = in[(long)(r0 + i) * 2304 + c0 + tx];
  __syncthreads();
  u16* out = v_t + (long)b * 768 * 1024;
  for (int i = ty; i < 32; i += 8)
    out[(long)(c0 + i) * 1024 + r0 + tx] = tile[tx][i];
}

// ---------------- masked softmax over rows of 1024 (bf16 -> bf16 P) ----------------
__global__ __launch_bounds__(256) void softmax_kernel(
    const u16* __restrict__ Sc, u16* __restrict__ P) {
  const long rb = (long)blockIdx.x * 1024;
  const int i = blockIdx.x & 1023;    // query index
  const int tid = threadIdx.x;
  const ushort4 sv = ((const ushort4*)(Sc + rb))[tid];
  float sl[4];
  const int j0 = tid * 4;
  sl[0] = (j0 + 0 <= i) ? -1e9f : bf2f(sv.x);
  sl[1] = (j0 + 1 <= i) ? -1e9f : bf2f(sv.y);
  sl[2] = (j0 + 2 <= i) ? -1e9f : bf2f(sv.z);
  sl[3] = (j0 + 3 <= i) ? -1e9f : bf2f(sv.w);
  float mx = fmaxf(fmaxf(sl[0], sl[1]), fmaxf(sl[2], sl[3]));
  __shared__ float red[4];
#pragma unroll
  for (int off = 32; off > 0; off >>= 1) mx = fmaxf(mx, __shfl_down(mx, off));
  const int lane = tid & 63, wid = tid >> 6;
  if (lane == 0) red[wid] = mx;
  __syncthreads();
  mx = fmaxf(fmaxf(red[0], red[1]), fmaxf(red[2], red[3]));
  float p[4], sum = 0.f;
#pragma unroll
  for (int c = 0; c < 4; ++c) { p[c] = __expf(sl[c] - mx); sum += p[c]; }
  __syncthreads();
#pragma unroll
  for (int off = 32; off > 0; off >>= 1) sum += __shfl_down(sum, off);
  if (lane == 0) red[wid] = sum;
  __syncthreads();
  sum = red[0] + red[1] + red[2] + red[3];
  const float inv = 1.f / sum;
  u16* pr = P + rb + j0;
#pragma unroll
  for (int c = 0; c < 4; ++c) pr[c] = f2bf(p[c] * inv);
}

// ---------------- generic bf16 MFMA GEMM ----------------
// C = (A * Wt^T + bias) * (col<scale_ncols ? scale : 1) (+resid)(relu)
// A: M x K (lda), Wt: N x K (ldw). z-batched: zq=z/zdiv, zr=z%zdiv.
// REMAP: 1-D grid; groups of 128 blocks = 8 col-panels x 16 row-blocks so that a
// panel's row-blocks land stride-8 apart (same XCD under round-robin dispatch).
template <int BM, int BN, int FM, int FN, bool REMAP>
__global__ __launch_bounds__(256) void gemm_bf16(
    const u16* __restrict__ A, const u16* __restrict__ Wt,
    const float* __restrict__ bias, const float* resid,
    float* outF, u16* outB,
    int K, int lda, int ldw, int ldc,
    long sA1, long sA2, long sW1, long sW2, long sC1, long sC2,
    int zdiv, int Nreal, float scale, int scale_ncols, int relu) {
  __shared__ u16 As[BM * 32];
  __shared__ u16 Bs[BN * 32];

  const int z = blockIdx.z;
  const int zq = z / zdiv, zr = z % zdiv;
  A += (long)zq * sA1 + (long)zr * sA2;
  Wt += (long)zq * sW1 + (long)zr * sW2;
  const long coff = (long)zq * sC1 + (long)zr * sC2;

  const int tid = threadIdx.x;
  const int lane = tid & 63;
  const int wid = tid >> 6;
  const int wm = wid >> 1, wn = wid & 1;
  const int lrow = lane & 15, kgrp = lane >> 4;

  long row0, col0;
  if (REMAP) {
    const int flat = blockIdx.x;
    const int g = flat >> 7, rem = flat & 127;
    const int fullg = gridDim.x >> 7;
    int panel, rb;
    if (g < fullg) { panel = g * 8 + (rem & 7); rb = rem >> 3; }
    else           { panel = fullg * 8 + (rem >> 4); rb = rem & 15; }
    row0 = (long)rb * BM;
    col0 = (long)panel * BN;
  } else {
    row0 = (long)blockIdx.y * BM;
    col0 = (long)blockIdx.x * BN;
  }

  f32x4 acc[FM][FN];
#pragma unroll
  for (int m = 0; m < FM; ++m)
#pragma unroll
    for (int n = 0; n < FN; ++n) acc[m][n] = (f32x4){0.f, 0.f, 0.f, 0.f};

  constexpr int ACALLS = (BM * 64) / 4096;
  constexpr int BCALLS = (BN * 64) / 4096;

  for (int k0 = 0; k0 < K; k0 += 32) {
    __syncthreads();
#pragma unroll
    for (int c = 0; c < ACALLS; ++c) {
      const int o = c * 4096 + tid * 16;
      const int r = o >> 6;
      const int kb = (o & 63) >> 1;
      load_lds16(A + (row0 + r) * lda + k0 + kb, (char*)As + o);
    }
#pragma unroll
    for (int c = 0; c < BCALLS; ++c) {
      const int o = c * 4096 + tid * 16;
      const int r = o >> 6;
      const int kb = (o & 63) >> 1;
      load_lds16(Wt + (col0 + r) * ldw + k0 + kb, (char*)Bs + o);
    }
    __syncthreads();

    bf16x8 af[FM], bfr[FN];
#pragma unroll
    for (int m = 0; m < FM; ++m)
      af[m] = *(const bf16x8*)&As[(wm * FM * 16 + m * 16 + lrow) * 32 + kgrp * 8];
#pragma unroll
    for (int n = 0; n < FN; ++n)
      bfr[n] = *(const bf16x8*)&Bs[(wn * FN * 16 + n * 16 + lrow) * 32 + kgrp * 8];
#pragma unroll
    for (int m = 0; m < FM; ++m)
#pragma unroll
      for (int n = 0; n < FN; ++n)
        acc[m][n] = __builtin_amdgcn_mfma_f32_16x16x32_bf16(af[m], bfr[n], acc[m][n], 0, 0, 0);
  }

#pragma unroll
  for (int m = 0; m < FM; ++m) {
    const long row = row0 + wm * FM * 16 + m * 16 + kgrp * 4;
#pragma unroll
    for (int n = 0; n < FN; ++n) {
      const long col = col0 + wn * FN * 16 + n * 16 + lrow;
      if (col < Nreal) {
        const float bb = bias ? bias[col] : 0.f;
        const float sc = (col < scale_ncols) ? scale : 1.f;
#pragma unroll
        for (int r = 0; r < 4; ++r) {
          const long idx = coff + (row + r) * ldc + col;
          float v = (acc[m][n][r] + bb) * sc;
          if (resid) v += resid[idx];
          if (relu) v = fmaxf(v, 0.f);
          if (outF) outF[idx] = v;
          else outB[idx] = f2bf(v);
        }
      }
    }
  }
}

extern "C" void kernel_launch(void* const* d_in, const int* in_sizes, int n_in,
                              void* d_out, int out_size, void* d_ws, size_t ws_size,
                              hipStream_t stream) {
  const int* x = (const int*)d_in[0];
  const float* tok_emb = (const float*)d_in[1];
  const float* Wq = (const float*)d_in[2];
  const float* bq = (const float*)d_in[3];
  const float* Wk = (const float*)d_in[4];
  const float* bk = (const float*)d_in[5];
  const float* Wv = (const float*)d_in[6];
  const float* bv = (const float*)d_in[7];
  const float* Wo = (const float*)d_in[8];
  const float* bo = (const float*)d_in[9];
  const float* ln1g = (const float*)d_in[10];
  const float* ln1b = (const float*)d_in[11];
  const float* ln2g = (const float*)d_in[12];
  const float* ln2b = (const float*)d_in[13];
  const float* W1 = (const float*)d_in[14];
  const float* b1 = (const float*)d_in[15];
  const float* W2 = (const float*)d_in[16];
  const float* b2 = (const float*)d_in[17];
  const float* lnfg = (const float*)d_in[18];
  const float* lnfb = (const float*)d_in[19];
  const float* Wout = (const float*)d_in[20];
  const float* bout = (const float*)d_in[21];

  char* p = (char*)d_ws;
  auto alloc = [&](size_t bytes) {
    void* r = (void*)p;
    p += (bytes + 255) & ~(size_t)255;
    return r;
  };
  float* h = (float*)alloc(2048L * 768 * 4);
  u16* y = (u16*)alloc(2048L * 768 * 2);
  u16* qkv = (u16*)alloc(2048L * 2304 * 2);
  u16* v_t = (u16*)alloc(2L * 768 * 1024 * 2);
  u16* att = (u16*)alloc(2048L * 768 * 2);
  u16* mid = (u16*)alloc(2048L * 3072 * 2);
  u16* qkv_t = (u16*)alloc(2304L * 768 * 2);
  u16* wo_t = (u16*)alloc(768L * 768 * 2);
  u16* w1_t = (u16*)alloc(768L * 3072 * 2);
  u16* w2_t = (u16*)alloc(768L * 3072 * 2);
  u16* wout_t = (u16*)alloc(50304L * 768 * 2);
  float* bqkv = (float*)alloc(2304L * 4);

  u16* scores = (u16*)d_out;                           // 24*1024*1024 bf16 = 50 MB
  u16* P = (u16*)((char*)d_out + 50331648);            // 24*1024*1024 bf16

  const dim3 tb(256);
  const dim3 cb(32, 8);

  embed_kernel<<<2048, tb, 0, stream>>>(x, tok_emb, h);

  // vocab weight conversion (independent of layers)
  conv_transpose<<<dim3(1572, 24), cb, 0, stream>>>(Wout, wout_t, 768, 50257, 50304);

  for (int l = 0; l < 12; ++l) {
    conv_qkvo<<<dim3(24, 24, 4), cb, 0, stream>>>(
        Wq + l * 589824L, Wk + l * 589824L, Wv + l * 589824L, Wo + l * 589824L,
        qkv_t, wo_t);
    conv_transpose<<<dim3(96, 24), cb, 0, stream>>>(W1 + l * 2359296L, w1_t, 768, 3072, 3072);
    conv_transpose<<<dim3(24, 96), cb, 0, stream>>>(W2 + l * 2359296L, w2_t, 3072, 768, 768);
    concat3<<<9, tb, 0, stream>>>(bq + l * 768, bk + l * 768, bv + l * 768, bqkv);

    ln_kernel<<<2048, tb, 0, stream>>>(h, ln1g + l * 768, ln1b + l * 768, y);

    // fused QKV: qkv = (y @ [Wq|Wk|Wv] + bqkv), q columns scaled by 1/8
    gemm_bf16<64, 64, 2, 2, false><<<dim3(36, 32, 1), tb, 0, stream>>>(
        y, qkv_t, bqkv, nullptr, nullptr, qkv,
        768, 768, 768, 2304, 0, 0, 0, 0, 0, 0, 1, 2304, 0.125f, 768, 0);

    transpose_v<<<dim3(24, 32, 2), cb, 0, stream>>>(qkv, v_t);

    // scores = q @ k^T (bf16 out), z = b*12 + h
    gemm_bf16<128, 128, 4, 4, false><<<dim3(8, 8, 24), tb, 0, stream>>>(
        qkv, qkv + 768, nullptr, nullptr, nullptr, scores,
        64, 2304, 2304, 1024,
        2359296L, 64L, 2359296L, 64L, 12582912L, 1048576L, 12, 1024, 1.f, 0, 0);

    softmax_kernel<<<24576, tb, 0, stream>>>(scores, P);

    // att = P @ V  (Wt = v_t: 64 x 1024 per head)
    gemm_bf16<64, 64, 2, 2, false><<<dim3(1, 16, 24), tb, 0, stream>>>(
        P, v_t, nullptr, nullptr, nullptr, att,
        1024, 1024, 1024, 768,
        12582912L, 1048576L, 786432L, 65536L, 786432L, 64L, 12, 64, 1.f, 0, 0);

    // h += att @ Wo + bo
    gemm_bf16<64, 64, 2, 2, false><<<dim3(12, 32, 1), tb, 0, stream>>>(
        att, wo_t, bo + l * 768, h, h, nullptr,
        768, 768, 768, 768, 0, 0, 0, 0, 0, 0, 1, 768, 1.f, 0, 0);

    ln_kernel<<<2048, tb, 0, stream>>>(h, ln2g + l * 768, ln2b + l * 768, y);

    // mid = relu(y @ W1 + b1)
    gemm_bf16<128, 128, 4, 4, false><<<dim3(24, 16, 1), tb, 0, stream>>>(
        y, w1_t, b1 + l * 3072, nullptr, nullptr, mid,
        768, 768, 768, 3072, 0, 0, 0, 0, 0, 0, 1, 3072, 1.f, 0, 1);

    // h += mid @ W2 + b2
    gemm_bf16<64, 64, 2, 2, false><<<dim3(12, 32, 1), tb, 0, stream>>>(
        mid, w2_t, b2 + l * 768, h, h, nullptr,
        3072, 3072, 3072, 768, 0, 0, 0, 0, 0, 0, 1, 768, 1.f, 0, 0);
  }

  ln_kernel<<<2048, tb, 0, stream>>>(h, lnfg, lnfb, y);

  // logits = y @ Wout + bout  (remapped 1-D grid: 393 panels x 16 row-blocks)
  gemm_bf16<128, 128, 4, 4, true><<<dim3(6288, 1, 1), tb, 0, stream>>>(
      y, wout_t, bout, nullptr, (float*)d_out, nullptr,
      768, 768, 768, 50257, 0, 0, 0, 0, 0, 0, 1, 50257, 1.f, 0, 0);
}

// Round 3
// 2565.112 us; speedup vs baseline: 1.8280x; 1.1744x over previous
//
#include <hip/hip_runtime.h>
#include <hip/hip_bf16.h>
#include <stdint.h>

typedef __attribute__((ext_vector_type(8))) short bf16x8;
typedef __attribute__((ext_vector_type(4))) float f32x4;
typedef unsigned short u16;
typedef unsigned int u32;

__device__ inline float bf2f(u16 u) {
  unsigned int x = ((unsigned int)u) << 16;
  return __builtin_bit_cast(float, x);
}
__device__ inline u16 f2bf(float f) {
  unsigned int x = __builtin_bit_cast(unsigned int, f);
  unsigned int r = x + 0x7fffu + ((x >> 16) & 1u);
  return (u16)(r >> 16);
}

__device__ inline void load_lds16(const void* g, void* l) {
  __builtin_amdgcn_global_load_lds(
      (const __attribute__((address_space(1))) unsigned int*)g,
      (__attribute__((address_space(3))) unsigned int*)l, 16, 0, 0);
}

// swizzled byte offset within a 64-row x 128-byte LDS tile
#define SWB(r, cb) (((r) << 7) + ((cb) ^ (((r) & 7) << 4)))

// ---------------- embedding + positional encoding ----------------
__global__ __launch_bounds__(256) void embed_kernel(
    const int* __restrict__ x, const float* __restrict__ emb,
    float* __restrict__ h) {
  const int row = blockIdx.x;          // b*1024 + s
  const int s = row & 1023;
  const int tok = x[row];
  const int tid = threadIdx.x;
  const float c = -logf(10000.f) / 768.f;
#pragma unroll
  for (int i = 0; i < 3; ++i) {
    const int d = tid + i * 256;
    const int deven = d & ~1;
    const float ang = (float)s * expf((float)deven * c);
    const float pe = (d & 1) ? cosf(ang) : sinf(ang);
    h[(long)row * 768 + d] = emb[(long)tok * 768 + d] * 27.712812921102035f + pe;
  }
}

// ---------------- layernorm (f32 in -> bf16 out) ----------------
__global__ __launch_bounds__(256) void ln_kernel(
    const float* __restrict__ X, const float* __restrict__ g,
    const float* __restrict__ b, u16* __restrict__ Y) {
  const int row = blockIdx.x;
  const float* xr = X + (long)row * 768;
  const int tid = threadIdx.x;
  float v[3];
  float s = 0.f, sq = 0.f;
#pragma unroll
  for (int i = 0; i < 3; ++i) {
    v[i] = xr[tid + i * 256];
    s += v[i];
    sq += v[i] * v[i];
  }
  __shared__ float red[8];
#pragma unroll
  for (int off = 32; off > 0; off >>= 1) {
    s += __shfl_down(s, off);
    sq += __shfl_down(sq, off);
  }
  const int lane = tid & 63, wid = tid >> 6;
  if (lane == 0) { red[wid] = s; red[wid + 4] = sq; }
  __syncthreads();
  s = red[0] + red[1] + red[2] + red[3];
  sq = red[4] + red[5] + red[6] + red[7];
  const float mean = s * (1.f / 768.f);
  const float var = sq * (1.f / 768.f) - mean * mean;
  const float rs = rsqrtf(var + 1e-5f);
  u16* yr = Y + (long)row * 768;
#pragma unroll
  for (int i = 0; i < 3; ++i) {
    const int d = tid + i * 256;
    yr[d] = f2bf((v[i] - mean) * rs * g[d] + b[d]);
  }
}

// ---------------- f32 (K x N) -> bf16 transposed (Npad x K) ----------------
__global__ void conv_transpose(const float* __restrict__ W, u16* __restrict__ Wt,
                               int K, int N, int Npad) {
  __shared__ float tile[32][33];
  const int n0 = blockIdx.x * 32, k0 = blockIdx.y * 32;
  const int tx = threadIdx.x, ty = threadIdx.y;
  for (int i = ty; i < 32; i += 8) {
    const int n = n0 + tx;
    tile[i][tx] = (n < N) ? W[(long)(k0 + i) * N + n] : 0.f;
  }
  __syncthreads();
  for (int i = ty; i < 32; i += 8) {
    const int n = n0 + i;
    if (n < Npad) Wt[(long)n * K + k0 + tx] = f2bf(tile[tx][i]);
  }
}

// ---- merged Wq/Wk/Wv/Wo conversion (all 768x768), z = which ----
__global__ void conv_qkvo(const float* __restrict__ Wq, const float* __restrict__ Wk,
                          const float* __restrict__ Wv, const float* __restrict__ Wo,
                          u16* __restrict__ qkv_t, u16* __restrict__ wo_t) {
  __shared__ float tile[32][33];
  const int z = blockIdx.z;
  const float* W = (z == 0) ? Wq : (z == 1) ? Wk : (z == 2) ? Wv : Wo;
  u16* dst = (z < 3) ? qkv_t + (long)z * 768 * 768 : wo_t;
  const int n0 = blockIdx.x * 32, k0 = blockIdx.y * 32;
  const int tx = threadIdx.x, ty = threadIdx.y;
  for (int i = ty; i < 32; i += 8)
    tile[i][tx] = W[(long)(k0 + i) * 768 + n0 + tx];
  __syncthreads();
  for (int i = ty; i < 32; i += 8)
    dst[(long)(n0 + i) * 768 + k0 + tx] = f2bf(tile[tx][i]);
}

// ---- bias concat: bqkv = [bq, bk, bv] ----
__global__ void concat3(const float* __restrict__ a, const float* __restrict__ b,
                        const float* __restrict__ c, float* __restrict__ o) {
  const int i = blockIdx.x * 256 + threadIdx.x;
  if (i < 2304)
    o[i] = (i < 768) ? a[i] : (i < 1536) ? b[i - 768] : c[i - 1536];
}

// ---- v segment of qkv [2048][2304] -> v_t [2][768][1024] ----
__global__ void transpose_v(const u16* __restrict__ qkv, u16* __restrict__ v_t) {
  __shared__ u16 tile[32][33];
  const int b = blockIdx.z;
  const int c0 = blockIdx.x * 32;   // over 768 v-cols
  const int r0 = blockIdx.y * 32;   // over 1024 seq
  const int tx = threadIdx.x, ty = threadIdx.y;
  const u16* in = qkv + (long)b * 1024 * 2304 + 1536;
  for (int i = ty; i < 32; i += 8)
    tile[i][tx] = in[(long)(r0 + i) * 2304 + c0 + tx];
  __syncthreads();
  u16* out = v_t + (long)b * 768 * 1024;
  for (int i = ty; i < 32; i += 8)
    out[(long)(c0 + i) * 1024 + r0 + tx] = tile[tx][i];
}

// ---------------- flash attention ----------------
// grid (16 qtiles, 12 heads, 2 batch), 256 threads = 4 waves.
// Wave w owns q-rows w*16..w*16+15 (on lane&15) and all 64 keys of each tile.
// S^T = mfma(K, Q) so q-row is the C column (lane&15): softmax state is per-lane.
__global__ __launch_bounds__(256) void flash_attn(
    const u16* __restrict__ qkv, const u16* __restrict__ v_t,
    u16* __restrict__ att) {
  __shared__ u16 Qs[4096];   // [64 q-rows][64 d], swizzled
  __shared__ u16 Ks[4096];   // [64 keys][64 d], swizzled
  __shared__ u16 Vs[4096];   // [64 d][64 keys] (V^T), swizzled
  __shared__ u16 Ps[4096];   // per-wave [16 q-rows][64 keys], swizzled

  const int qt = blockIdx.x, hh = blockIdx.y, b = blockIdx.z;
  const int tid = threadIdx.x, lane = tid & 63, w = tid >> 6;
  const int q = lane & 15, g = lane >> 4;
  const int q0 = qt * 64;

  // stage Q (q columns of qkv already scaled by 1/8)
#pragma unroll
  for (int c = 0; c < 2; ++c) {
    const int o = c * 4096 + tid * 16;
    const int r = o >> 7, cb = o & 127;
    const int cbs = cb ^ ((r & 7) << 4);
    load_lds16(qkv + ((long)(b * 1024 + q0 + r)) * 2304 + hh * 64 + (cbs >> 1),
               (char*)Qs + o);
  }
  __syncthreads();
  bf16x8 qf[2];
#pragma unroll
  for (int c = 0; c < 2; ++c)
    qf[c] = *(const bf16x8*)((char*)Qs + SWB(w * 16 + q, c * 64 + g * 16));

  const int i_lane = q0 + w * 16 + q;
  float m = -1e30f, l = 0.f;
  f32x4 out[4];
#pragma unroll
  for (int t = 0; t < 4; ++t) out[t] = (f32x4){0.f, 0.f, 0.f, 0.f};
  u16* Pw = Ps + w * 1024;

  for (int kt = 0; kt < 16; ++kt) {
    __syncthreads();
#pragma unroll
    for (int c = 0; c < 2; ++c) {
      const int o = c * 4096 + tid * 16;
      const int r = o >> 7, cb = o & 127;
      const int cbs = cb ^ ((r & 7) << 4);
      load_lds16(qkv + ((long)(b * 1024 + kt * 64 + r)) * 2304 + 768 + hh * 64 + (cbs >> 1),
                 (char*)Ks + o);
      load_lds16(v_t + ((long)(b * 768 + hh * 64 + r)) * 1024 + kt * 64 + (cbs >> 1),
                 (char*)Vs + o);
    }
    __syncthreads();

    // S^T = K . Q^T  (rows=keys, cols=q-rows)
    f32x4 acc[4];
#pragma unroll
    for (int t = 0; t < 4; ++t) acc[t] = (f32x4){0.f, 0.f, 0.f, 0.f};
#pragma unroll
    for (int c = 0; c < 2; ++c) {
      const bf16x8 qq = qf[c];
#pragma unroll
      for (int t = 0; t < 4; ++t) {
        const bf16x8 kf = *(const bf16x8*)((char*)Ks + SWB(t * 16 + q, c * 64 + g * 16));
        acc[t] = __builtin_amdgcn_mfma_f32_16x16x32_bf16(kf, qq, acc[t], 0, 0, 0);
      }
    }

    // mask (bug preserved: allowed keys j<=i get -1e9) + tile max
    float s[4][4];
    float tmax = -1e30f;
#pragma unroll
    for (int t = 0; t < 4; ++t)
#pragma unroll
      for (int r = 0; r < 4; ++r) {
        const int j = kt * 64 + t * 16 + g * 4 + r;
        const float v = (j <= i_lane) ? -1e9f : acc[t][r];
        s[t][r] = v;
        tmax = fmaxf(tmax, v);
      }
    tmax = fmaxf(tmax, __shfl_xor(tmax, 16));
    tmax = fmaxf(tmax, __shfl_xor(tmax, 32));
    const float mn = fmaxf(m, tmax);
    const float sf = __expf(m - mn);
    m = mn;
    float rs = 0.f;
    u16 pb[4][4];
#pragma unroll
    for (int t = 0; t < 4; ++t)
#pragma unroll
      for (int r = 0; r < 4; ++r) {
        const float pv = __expf(s[t][r] - mn);
        rs += pv;
        pb[t][r] = f2bf(pv);
      }
    rs += __shfl_xor(rs, 16);
    rs += __shfl_xor(rs, 32);
    l = l * sf + rs;
#pragma unroll
    for (int t = 0; t < 4; ++t)
#pragma unroll
      for (int r = 0; r < 4; ++r) out[t][r] *= sf;

    // P^T -> per-wave LDS, stored [qrow][key] (swizzled rows)
#pragma unroll
    for (int t = 0; t < 4; ++t) {
      uint2 pk;
      pk.x = (u32)pb[t][0] | ((u32)pb[t][1] << 16);
      pk.y = (u32)pb[t][2] | ((u32)pb[t][3] << 16);
      *(uint2*)((char*)Pw + SWB(q, t * 32 + g * 8)) = pk;
    }

    // O^T += V^T . P^T
#pragma unroll
    for (int c = 0; c < 2; ++c) {
      const bf16x8 pf = *(const bf16x8*)((char*)Pw + SWB(q, c * 64 + g * 16));
#pragma unroll
      for (int t = 0; t < 4; ++t) {
        const bf16x8 vf = *(const bf16x8*)((char*)Vs + SWB(t * 16 + q, c * 64 + g * 16));
        out[t] = __builtin_amdgcn_mfma_f32_16x16x32_bf16(vf, pf, out[t], 0, 0, 0);
      }
    }
  }

  const float inv = 1.f / l;
  u16* arow = att + ((long)(b * 1024 + q0 + w * 16 + q)) * 768 + hh * 64;
#pragma unroll
  for (int t = 0; t < 4; ++t) {
    uint2 pk;
    pk.x = (u32)f2bf(out[t][0] * inv) | ((u32)f2bf(out[t][1] * inv) << 16);
    pk.y = (u32)f2bf(out[t][2] * inv) | ((u32)f2bf(out[t][3] * inv) << 16);
    *(uint2*)(arow + t * 16 + g * 4) = pk;
  }
}

// ---------------- generic bf16 MFMA GEMM, double-buffered (T3-min 2-phase) ----
template <int BM, int BN, int FM, int FN, bool REMAP>
__global__ __launch_bounds__(256) void gemm_bf16(
    const u16* __restrict__ A, const u16* __restrict__ Wt,
    const float* __restrict__ bias, const float* resid,
    float* outF, u16* outB,
    int K, int lda, int ldw, int ldc,
    long sA1, long sA2, long sW1, long sW2, long sC1, long sC2,
    int zdiv, int Nreal, float scale, int scale_ncols, int relu) {
  __shared__ u16 As[2][BM * 32];
  __shared__ u16 Bs[2][BN * 32];

  const int z = blockIdx.z;
  const int zq = z / zdiv, zr = z % zdiv;
  A += (long)zq * sA1 + (long)zr * sA2;
  Wt += (long)zq * sW1 + (long)zr * sW2;
  const long coff = (long)zq * sC1 + (long)zr * sC2;

  const int tid = threadIdx.x;
  const int lane = tid & 63;
  const int wid = tid >> 6;
  const int wm = wid >> 1, wn = wid & 1;
  const int lrow = lane & 15, kgrp = lane >> 4;

  long row0, col0;
  if (REMAP) {
    const int flat = blockIdx.x;
    const int g = flat >> 7, rem = flat & 127;
    const int fullg = gridDim.x >> 7;
    int panel, rb;
    if (g < fullg) { panel = g * 8 + (rem & 7); rb = rem >> 3; }
    else           { panel = fullg * 8 + (rem >> 4); rb = rem & 15; }
    row0 = (long)rb * BM;
    col0 = (long)panel * BN;
  } else {
    row0 = (long)blockIdx.y * BM;
    col0 = (long)blockIdx.x * BN;
  }

  f32x4 acc[FM][FN];
#pragma unroll
  for (int m = 0; m < FM; ++m)
#pragma unroll
    for (int n = 0; n < FN; ++n) acc[m][n] = (f32x4){0.f, 0.f, 0.f, 0.f};

  constexpr int ACALLS = (BM * 64) / 4096;
  constexpr int BCALLS = (BN * 64) / 4096;

  auto stage = [&](int buf, int k0) {
#pragma unroll
    for (int c = 0; c < ACALLS; ++c) {
      const int o = c * 4096 + tid * 16;
      const int r = o >> 6;
      const int kb = (o & 63) >> 1;
      load_lds16(A + (row0 + r) * lda + k0 + kb, (char*)As[buf] + o);
    }
#pragma unroll
    for (int c = 0; c < BCALLS; ++c) {
      const int o = c * 4096 + tid * 16;
      const int r = o >> 6;
      const int kb = (o & 63) >> 1;
      load_lds16(Wt + (col0 + r) * ldw + k0 + kb, (char*)Bs[buf] + o);
    }
  };

  stage(0, 0);
  __syncthreads();
  int cur = 0;
  for (int k0 = 0; k0 < K; k0 += 32) {
    if (k0 + 32 < K) stage(cur ^ 1, k0 + 32);

    bf16x8 af[FM], bfr[FN];
#pragma unroll
    for (int m = 0; m < FM; ++m)
      af[m] = *(const bf16x8*)&As[cur][(wm * FM * 16 + m * 16 + lrow) * 32 + kgrp * 8];
#pragma unroll
    for (int n = 0; n < FN; ++n)
      bfr[n] = *(const bf16x8*)&Bs[cur][(wn * FN * 16 + n * 16 + lrow) * 32 + kgrp * 8];
#pragma unroll
    for (int m = 0; m < FM; ++m)
#pragma unroll
      for (int n = 0; n < FN; ++n)
        acc[m][n] = __builtin_amdgcn_mfma_f32_16x16x32_bf16(af[m], bfr[n], acc[m][n], 0, 0, 0);

    __syncthreads();
    cur ^= 1;
  }

#pragma unroll
  for (int m = 0; m < FM; ++m) {
    const long row = row0 + wm * FM * 16 + m * 16 + kgrp * 4;
#pragma unroll
    for (int n = 0; n < FN; ++n) {
      const long col = col0 + wn * FN * 16 + n * 16 + lrow;
      if (col < Nreal) {
        const float bb = bias ? bias[col] : 0.f;
        const float sc = (col < scale_ncols) ? scale : 1.f;
#pragma unroll
        for (int r = 0; r < 4; ++r) {
          const long idx = coff + (row + r) * ldc + col;
          float v = (acc[m][n][r] + bb) * sc;
          if (resid) v += resid[idx];
          if (relu) v = fmaxf(v, 0.f);
          if (outF) outF[idx] = v;
          else outB[idx] = f2bf(v);
        }
      }
    }
  }
}

extern "C" void kernel_launch(void* const* d_in, const int* in_sizes, int n_in,
                              void* d_out, int out_size, void* d_ws, size_t ws_size,
                              hipStream_t stream) {
  const int* x = (const int*)d_in[0];
  const float* tok_emb = (const float*)d_in[1];
  const float* Wq = (const float*)d_in[2];
  const float* bq = (const float*)d_in[3];
  const float* Wk = (const float*)d_in[4];
  const float* bk = (const float*)d_in[5];
  const float* Wv = (const float*)d_in[6];
  const float* bv = (const float*)d_in[7];
  const float* Wo = (const float*)d_in[8];
  const float* bo = (const float*)d_in[9];
  const float* ln1g = (const float*)d_in[10];
  const float* ln1b = (const float*)d_in[11];
  const float* ln2g = (const float*)d_in[12];
  const float* ln2b = (const float*)d_in[13];
  const float* W1 = (const float*)d_in[14];
  const float* b1 = (const float*)d_in[15];
  const float* W2 = (const float*)d_in[16];
  const float* b2 = (const float*)d_in[17];
  const float* lnfg = (const float*)d_in[18];
  const float* lnfb = (const float*)d_in[19];
  const float* Wout = (const float*)d_in[20];
  const float* bout = (const float*)d_in[21];

  char* p = (char*)d_ws;
  auto alloc = [&](size_t bytes) {
    void* r = (void*)p;
    p += (bytes + 255) & ~(size_t)255;
    return r;
  };
  float* h = (float*)alloc(2048L * 768 * 4);
  u16* y = (u16*)alloc(2048L * 768 * 2);
  u16* qkv = (u16*)alloc(2048L * 2304 * 2);
  u16* v_t = (u16*)alloc(2L * 768 * 1024 * 2);
  u16* att = (u16*)alloc(2048L * 768 * 2);
  u16* mid = (u16*)alloc(2048L * 3072 * 2);
  u16* qkv_t = (u16*)alloc(2304L * 768 * 2);
  u16* wo_t = (u16*)alloc(768L * 768 * 2);
  u16* w1_t = (u16*)alloc(768L * 3072 * 2);
  u16* w2_t = (u16*)alloc(768L * 3072 * 2);
  u16* wout_t = (u16*)alloc(50304L * 768 * 2);
  float* bqkv = (float*)alloc(2304L * 4);

  const dim3 tb(256);
  const dim3 cb(32, 8);

  embed_kernel<<<2048, tb, 0, stream>>>(x, tok_emb, h);

  // vocab weight conversion (independent of layers)
  conv_transpose<<<dim3(1572, 24), cb, 0, stream>>>(Wout, wout_t, 768, 50257, 50304);

  for (int l = 0; l < 12; ++l) {
    conv_qkvo<<<dim3(24, 24, 4), cb, 0, stream>>>(
        Wq + l * 589824L, Wk + l * 589824L, Wv + l * 589824L, Wo + l * 589824L,
        qkv_t, wo_t);
    conv_transpose<<<dim3(96, 24), cb, 0, stream>>>(W1 + l * 2359296L, w1_t, 768, 3072, 3072);
    conv_transpose<<<dim3(24, 96), cb, 0, stream>>>(W2 + l * 2359296L, w2_t, 3072, 768, 768);
    concat3<<<9, tb, 0, stream>>>(bq + l * 768, bk + l * 768, bv + l * 768, bqkv);

    ln_kernel<<<2048, tb, 0, stream>>>(h, ln1g + l * 768, ln1b + l * 768, y);

    // fused QKV: qkv = (y @ [Wq|Wk|Wv] + bqkv), q columns scaled by 1/8
    gemm_bf16<128, 128, 4, 4, false><<<dim3(18, 16, 1), tb, 0, stream>>>(
        y, qkv_t, bqkv, nullptr, nullptr, qkv,
        768, 768, 768, 2304, 0, 0, 0, 0, 0, 0, 1, 2304, 0.125f, 768, 0);

    transpose_v<<<dim3(24, 32, 2), cb, 0, stream>>>(qkv, v_t);

    flash_attn<<<dim3(16, 12, 2), tb, 0, stream>>>(qkv, v_t, att);

    // h += att @ Wo + bo
    gemm_bf16<64, 64, 2, 2, false><<<dim3(12, 32, 1), tb, 0, stream>>>(
        att, wo_t, bo + l * 768, h, h, nullptr,
        768, 768, 768, 768, 0, 0, 0, 0, 0, 0, 1, 768, 1.f, 0, 0);

    ln_kernel<<<2048, tb, 0, stream>>>(h, ln2g + l * 768, ln2b + l * 768, y);

    // mid = relu(y @ W1 + b1)
    gemm_bf16<128, 128, 4, 4, false><<<dim3(24, 16, 1), tb, 0, stream>>>(
        y, w1_t, b1 + l * 3072, nullptr, nullptr, mid,
        768, 768, 768, 3072, 0, 0, 0, 0, 0, 0, 1, 3072, 1.f, 0, 1);

    // h += mid @ W2 + b2
    gemm_bf16<64, 64, 2, 2, false><<<dim3(12, 32, 1), tb, 0, stream>>>(
        mid, w2_t, b2 + l * 768, h, h, nullptr,
        3072, 3072, 3072, 768, 0, 0, 0, 0, 0, 0, 1, 768, 1.f, 0, 0);
  }

  ln_kernel<<<2048, tb, 0, stream>>>(h, lnfg, lnfb, y);

  // logits = y @ Wout + bout  (remapped 1-D grid: 393 panels x 16 row-blocks)
  gemm_bf16<128, 128, 4, 4, true><<<dim3(6288, 1, 1), tb, 0, stream>>>(
      y, wout_t, bout, nullptr, (float*)d_out, nullptr,
      768, 768, 768, 50257, 0, 0, 0, 0, 0, 0, 1, 50257, 1.f, 0, 0);
}

// Round 5
// 2456.392 us; speedup vs baseline: 1.9089x; 1.0443x over previous
//
#include <hip/hip_runtime.h>
#include <hip/hip_bf16.h>
#include <stdint.h>

typedef __attribute__((ext_vector_type(8))) short bf16x8;
typedef __attribute__((ext_vector_type(4))) float f32x4;
typedef unsigned short u16;
typedef unsigned int u32;

__device__ inline float bf2f(u16 u) {
  unsigned int x = ((unsigned int)u) << 16;
  return __builtin_bit_cast(float, x);
}
__device__ inline u16 f2bf(float f) {
  unsigned int x = __builtin_bit_cast(unsigned int, f);
  unsigned int r = x + 0x7fffu + ((x >> 16) & 1u);
  return (u16)(r >> 16);
}

__device__ inline void load_lds16(const void* g, void* l) {
  __builtin_amdgcn_global_load_lds(
      (const __attribute__((address_space(1))) unsigned int*)g,
      (__attribute__((address_space(3))) unsigned int*)l, 16, 0, 0);
}

template <int N>
__device__ inline void waitv() {
  if constexpr (N == 0) asm volatile("s_waitcnt vmcnt(0)" ::: "memory");
  else if constexpr (N == 2) asm volatile("s_waitcnt vmcnt(2)" ::: "memory");
  else if constexpr (N == 4) asm volatile("s_waitcnt vmcnt(4)" ::: "memory");
  else if constexpr (N == 8) asm volatile("s_waitcnt vmcnt(8)" ::: "memory");
}

// swizzled byte offset within a 64-row x 128-byte LDS tile
#define SWB(r, cb) (((r) << 7) + ((cb) ^ (((r) & 7) << 4)))

// ---------------- embedding + positional encoding ----------------
__global__ __launch_bounds__(256) void embed_kernel(
    const int* __restrict__ x, const float* __restrict__ emb,
    float* __restrict__ h) {
  const int row = blockIdx.x;          // b*1024 + s
  const int s = row & 1023;
  const int tok = x[row];
  const int tid = threadIdx.x;
  const float c = -logf(10000.f) / 768.f;
#pragma unroll
  for (int i = 0; i < 3; ++i) {
    const int d = tid + i * 256;
    const int deven = d & ~1;
    const float ang = (float)s * expf((float)deven * c);
    const float pe = (d & 1) ? cosf(ang) : sinf(ang);
    h[(long)row * 768 + d] = emb[(long)tok * 768 + d] * 27.712812921102035f + pe;
  }
}

// ---------------- layernorm (f32 in -> bf16 out) ----------------
__global__ __launch_bounds__(256) void ln_kernel(
    const float* __restrict__ X, const float* __restrict__ g,
    const float* __restrict__ b, u16* __restrict__ Y) {
  const int row = blockIdx.x;
  const float* xr = X + (long)row * 768;
  const int tid = threadIdx.x;
  float v[3];
  float s = 0.f, sq = 0.f;
#pragma unroll
  for (int i = 0; i < 3; ++i) {
    v[i] = xr[tid + i * 256];
    s += v[i];
    sq += v[i] * v[i];
  }
  __shared__ float red[8];
#pragma unroll
  for (int off = 32; off > 0; off >>= 1) {
    s += __shfl_down(s, off);
    sq += __shfl_down(sq, off);
  }
  const int lane = tid & 63, wid = tid >> 6;
  if (lane == 0) { red[wid] = s; red[wid + 4] = sq; }
  __syncthreads();
  s = red[0] + red[1] + red[2] + red[3];
  sq = red[4] + red[5] + red[6] + red[7];
  const float mean = s * (1.f / 768.f);
  const float var = sq * (1.f / 768.f) - mean * mean;
  const float rs = rsqrtf(var + 1e-5f);
  u16* yr = Y + (long)row * 768;
#pragma unroll
  for (int i = 0; i < 3; ++i) {
    const int d = tid + i * 256;
    yr[d] = f2bf((v[i] - mean) * rs * g[d] + b[d]);
  }
}

// ---------------- f32 (K x N) -> bf16 transposed (Npad x K) ----------------
__global__ void conv_transpose(const float* __restrict__ W, u16* __restrict__ Wt,
                               int K, int N, int Npad) {
  __shared__ float tile[32][33];
  const int n0 = blockIdx.x * 32, k0 = blockIdx.y * 32;
  const int tx = threadIdx.x, ty = threadIdx.y;
  for (int i = ty; i < 32; i += 8) {
    const int n = n0 + tx;
    tile[i][tx] = (n < N) ? W[(long)(k0 + i) * N + n] : 0.f;
  }
  __syncthreads();
  for (int i = ty; i < 32; i += 8) {
    const int n = n0 + i;
    if (n < Npad) Wt[(long)n * K + k0 + tx] = f2bf(tile[tx][i]);
  }
}

// ---- merged per-layer weight conversion: qkvo (4x 768x768) + W1 + W2 ----
__global__ void conv_all(const float* __restrict__ Wq, const float* __restrict__ Wk,
                         const float* __restrict__ Wv, const float* __restrict__ Wo,
                         const float* __restrict__ W1, const float* __restrict__ W2,
                         u16* __restrict__ qkv_t, u16* __restrict__ wo_t,
                         u16* __restrict__ w1_t, u16* __restrict__ w2_t) {
  __shared__ float tile[32][33];
  const int f = blockIdx.x;
  const float* W;
  u16* dst;
  int n0, k0, ldN, ldK;
  if (f < 2304) {
    const int z = f / 576, rem = f % 576;
    W = (z == 0) ? Wq : (z == 1) ? Wk : (z == 2) ? Wv : Wo;
    dst = (z < 3) ? qkv_t + (long)z * 768 * 768 : wo_t;
    n0 = (rem / 24) * 32; k0 = (rem % 24) * 32; ldN = 768; ldK = 768;
  } else if (f < 4608) {
    const int rem = f - 2304;
    W = W1; dst = w1_t;
    n0 = (rem / 24) * 32; k0 = (rem % 24) * 32; ldN = 3072; ldK = 768;
  } else {
    const int rem = f - 4608;
    W = W2; dst = w2_t;
    n0 = (rem / 96) * 32; k0 = (rem % 96) * 32; ldN = 768; ldK = 3072;
  }
  const int tx = threadIdx.x, ty = threadIdx.y;
  for (int i = ty; i < 32; i += 8)
    tile[i][tx] = W[(long)(k0 + i) * ldN + n0 + tx];
  __syncthreads();
  for (int i = ty; i < 32; i += 8)
    dst[(long)(n0 + i) * ldK + k0 + tx] = f2bf(tile[tx][i]);
}

// ---- all-layer bias concat: bqkv_all[l][2304] = [bq_l, bk_l, bv_l] ----
__global__ __launch_bounds__(256) void bias_all(
    const float* __restrict__ bq, const float* __restrict__ bk,
    const float* __restrict__ bv, float* __restrict__ o) {
  const int idx = blockIdx.x * 256 + threadIdx.x;
  const int l = idx / 2304, r = idx % 2304;
  o[idx] = (r < 768) ? bq[l * 768 + r]
         : (r < 1536) ? bk[l * 768 + r - 768] : bv[l * 768 + r - 1536];
}

// ---- v segment of qkv [2048][2304] -> v_t [2][768][1024] ----
__global__ void transpose_v(const u16* __restrict__ qkv, u16* __restrict__ v_t) {
  __shared__ u16 tile[32][33];
  const int b = blockIdx.z;
  const int c0 = blockIdx.x * 32;
  const int r0 = blockIdx.y * 32;
  const int tx = threadIdx.x, ty = threadIdx.y;
  const u16* in = qkv + (long)b * 1024 * 2304 + 1536;
  for (int i = ty; i < 32; i += 8)
    tile[i][tx] = in[(long)(r0 + i) * 2304 + c0 + tx];
  __syncthreads();
  u16* out = v_t + (long)b * 768 * 1024;
  for (int i = ty; i < 32; i += 8)
    out[(long)(c0 + i) * 1024 + r0 + tx] = tile[tx][i];
}

// ---------------- flash attention (dbuf K/V, causal tile skip) ----------------
__global__ __launch_bounds__(256) void flash_attn(
    const u16* __restrict__ qkv, const u16* __restrict__ v_t,
    u16* __restrict__ att) {
  __shared__ u16 Qs[4096];      // 8192 B: 64 rows x 128 B, swizzled
  __shared__ u16 Ks[2][4096];
  __shared__ u16 Vs[2][4096];
  __shared__ u16 Ps[4096];

  const int qt = blockIdx.x, hh = blockIdx.y, b = blockIdx.z;
  const int tid = threadIdx.x, lane = tid & 63, w = tid >> 6;
  const int q = lane & 15, g = lane >> 4;
  const int q0 = qt * 64;
  // tiles kt<qt are fully masked (-1e9): exact zero contribution, skip.
  // qt==15 keeps all tiles so the fully-masked row 1023 reproduces uniform 1/1024.
  const int kt0 = (qt < 15) ? qt : 0;

  auto stageKV = [&](int buf, int kt) {
#pragma unroll
    for (int c = 0; c < 2; ++c) {
      const int o = c * 4096 + tid * 16;     // byte offset in [0, 8192)
      const int r = o >> 7, cb = o & 127;
      const int cbs = cb ^ ((r & 7) << 4);
      load_lds16(qkv + ((long)(b * 1024 + kt * 64 + r)) * 2304 + 768 + hh * 64 + (cbs >> 1),
                 (char*)Ks[buf] + o);
      load_lds16(v_t + ((long)(b * 768 + hh * 64 + r)) * 1024 + kt * 64 + (cbs >> 1),
                 (char*)Vs[buf] + o);
    }
  };

  // stage Q + first K/V tile
#pragma unroll
  for (int c = 0; c < 2; ++c) {
    const int o = c * 4096 + tid * 16;
    const int r = o >> 7, cb = o & 127;
    const int cbs = cb ^ ((r & 7) << 4);
    load_lds16(qkv + ((long)(b * 1024 + q0 + r)) * 2304 + hh * 64 + (cbs >> 1),
               (char*)Qs + o);
  }
  stageKV(0, kt0);
  waitv<4>();
  __builtin_amdgcn_sched_barrier(0);
  __builtin_amdgcn_s_barrier();
  __builtin_amdgcn_sched_barrier(0);

  bf16x8 qf[2];
#pragma unroll
  for (int c = 0; c < 2; ++c)
    qf[c] = *(const bf16x8*)((char*)Qs + SWB(w * 16 + q, c * 64 + g * 16));

  const int i_lane = q0 + w * 16 + q;
  float m = -1e30f, l = 0.f;
  f32x4 out[4];
#pragma unroll
  for (int t = 0; t < 4; ++t) out[t] = (f32x4){0.f, 0.f, 0.f, 0.f};
  u16* Pw = Ps + w * 1024;

  int cur = 0;
  for (int kt = kt0; kt < 16; ++kt) {
    if (kt + 1 < 16) { stageKV(cur ^ 1, kt + 1); waitv<4>(); }
    else waitv<0>();
    __builtin_amdgcn_sched_barrier(0);
    __builtin_amdgcn_s_barrier();
    __builtin_amdgcn_sched_barrier(0);

    // S^T = K . Q^T
    f32x4 acc[4];
#pragma unroll
    for (int t = 0; t < 4; ++t) acc[t] = (f32x4){0.f, 0.f, 0.f, 0.f};
#pragma unroll
    for (int c = 0; c < 2; ++c) {
      const bf16x8 qq = qf[c];
#pragma unroll
      for (int t = 0; t < 4; ++t) {
        const bf16x8 kf = *(const bf16x8*)((char*)Ks[cur] + SWB(t * 16 + q, c * 64 + g * 16));
        acc[t] = __builtin_amdgcn_mfma_f32_16x16x32_bf16(kf, qq, acc[t], 0, 0, 0);
      }
    }

    // mask (bug preserved: allowed keys j<=i get -1e9) + tile max
    float s[4][4];
    float tmax = -1e30f;
#pragma unroll
    for (int t = 0; t < 4; ++t)
#pragma unroll
      for (int r = 0; r < 4; ++r) {
        const int j = kt * 64 + t * 16 + g * 4 + r;
        const float v = (j <= i_lane) ? -1e9f : acc[t][r];
        s[t][r] = v;
        tmax = fmaxf(tmax, v);
      }
    tmax = fmaxf(tmax, __shfl_xor(tmax, 16));
    tmax = fmaxf(tmax, __shfl_xor(tmax, 32));
    const float mn = fmaxf(m, tmax);
    const float sf = __expf(m - mn);
    m = mn;
    float rs = 0.f;
    u16 pb[4][4];
#pragma unroll
    for (int t = 0; t < 4; ++t)
#pragma unroll
      for (int r = 0; r < 4; ++r) {
        const float pv = __expf(s[t][r] - mn);
        rs += pv;
        pb[t][r] = f2bf(pv);
      }
    rs += __shfl_xor(rs, 16);
    rs += __shfl_xor(rs, 32);
    l = l * sf + rs;
#pragma unroll
    for (int t = 0; t < 4; ++t)
#pragma unroll
      for (int r = 0; r < 4; ++r) out[t][r] *= sf;

    // P^T -> per-wave LDS
#pragma unroll
    for (int t = 0; t < 4; ++t) {
      uint2 pk;
      pk.x = (u32)pb[t][0] | ((u32)pb[t][1] << 16);
      pk.y = (u32)pb[t][2] | ((u32)pb[t][3] << 16);
      *(uint2*)((char*)Pw + SWB(q, t * 32 + g * 8)) = pk;
    }

    // O^T += V^T . P^T
#pragma unroll
    for (int c = 0; c < 2; ++c) {
      const bf16x8 pf = *(const bf16x8*)((char*)Pw + SWB(q, c * 64 + g * 16));
#pragma unroll
      for (int t = 0; t < 4; ++t) {
        const bf16x8 vf = *(const bf16x8*)((char*)Vs[cur] + SWB(t * 16 + q, c * 64 + g * 16));
        out[t] = __builtin_amdgcn_mfma_f32_16x16x32_bf16(vf, pf, out[t], 0, 0, 0);
      }
    }
    __builtin_amdgcn_sched_barrier(0);
    __builtin_amdgcn_s_barrier();
    __builtin_amdgcn_sched_barrier(0);
    cur ^= 1;
  }

  const float inv = 1.f / l;
  u16* arow = att + ((long)(b * 1024 + q0 + w * 16 + q)) * 768 + hh * 64;
#pragma unroll
  for (int t = 0; t < 4; ++t) {
    uint2 pk;
    pk.x = (u32)f2bf(out[t][0] * inv) | ((u32)f2bf(out[t][1] * inv) << 16);
    pk.y = (u32)f2bf(out[t][2] * inv) | ((u32)f2bf(out[t][3] * inv) << 16);
    *(uint2*)(arow + t * 16 + g * 4) = pk;
  }
}

// ---------------- generic bf16 MFMA GEMM, depth-3 counted-vmcnt pipeline ----
template <int BM, int BN, int FM, int FN, bool REMAP>
__global__ __launch_bounds__(256) void gemm_bf16(
    const u16* __restrict__ A, const u16* __restrict__ Wt,
    const float* __restrict__ bias, const float* resid,
    float* outF, u16* outB,
    int K, int lda, int ldw, int ldc,
    long sA1, long sA2, long sW1, long sW2, long sC1, long sC2,
    int zdiv, int Nreal, float scale, int scale_ncols, int relu) {
  __shared__ u16 As[3][BM * 32];
  __shared__ u16 Bs[3][BN * 32];

  const int z = blockIdx.z;
  const int zq = z / zdiv, zr = z % zdiv;
  A += (long)zq * sA1 + (long)zr * sA2;
  Wt += (long)zq * sW1 + (long)zr * sW2;
  const long coff = (long)zq * sC1 + (long)zr * sC2;

  const int tid = threadIdx.x;
  const int lane = tid & 63;
  const int wid = tid >> 6;
  const int wm = wid >> 1, wn = wid & 1;
  const int lrow = lane & 15, kgrp = lane >> 4;

  long row0, col0;
  if (REMAP) {
    const int flat = blockIdx.x;
    const int g = flat >> 7, rem = flat & 127;
    const int fullg = gridDim.x >> 7;
    int panel, rb;
    if (g < fullg) { panel = g * 8 + (rem & 7); rb = rem >> 3; }
    else           { panel = fullg * 8 + (rem >> 4); rb = rem & 15; }
    row0 = (long)rb * BM;
    col0 = (long)panel * BN;
  } else {
    row0 = (long)blockIdx.y * BM;
    col0 = (long)blockIdx.x * BN;
  }

  f32x4 acc[FM][FN];
#pragma unroll
  for (int m = 0; m < FM; ++m)
#pragma unroll
    for (int n = 0; n < FN; ++n) acc[m][n] = (f32x4){0.f, 0.f, 0.f, 0.f};

  constexpr int ACALLS = (BM * 64) / 4096;
  constexpr int BCALLS = (BN * 64) / 4096;
  constexpr int LD = ACALLS + BCALLS;   // loads per stage per thread

  auto stage = [&](int buf, int k0) {
#pragma unroll
    for (int c = 0; c < ACALLS; ++c) {
      const int o = c * 4096 + tid * 16;
      const int r = o >> 6;
      const int kb = (o & 63) >> 1;
      load_lds16(A + (row0 + r) * lda + k0 + kb, (char*)As[buf] + o);
    }
#pragma unroll
    for (int c = 0; c < BCALLS; ++c) {
      const int o = c * 4096 + tid * 16;
      const int r = o >> 6;
      const int kb = (o & 63) >> 1;
      load_lds16(Wt + (col0 + r) * ldw + k0 + kb, (char*)Bs[buf] + o);
    }
  };

  const int T = K >> 5;
  stage(0, 0);
  stage(1, 32);
  int bcur = 0, bst = 2;
  for (int t = 0; t < T; ++t) {
    if (t + 2 < T) { stage(bst, (t + 2) * 32); waitv<2 * LD>(); }
    else if (t + 1 < T) waitv<LD>();
    else waitv<0>();
    __builtin_amdgcn_sched_barrier(0);
    __builtin_amdgcn_s_barrier();
    __builtin_amdgcn_sched_barrier(0);

    bf16x8 af[FM], bfr[FN];
#pragma unroll
    for (int m = 0; m < FM; ++m)
      af[m] = *(const bf16x8*)&As[bcur][(wm * FM * 16 + m * 16 + lrow) * 32 + kgrp * 8];
#pragma unroll
    for (int n = 0; n < FN; ++n)
      bfr[n] = *(const bf16x8*)&Bs[bcur][(wn * FN * 16 + n * 16 + lrow) * 32 + kgrp * 8];
#pragma unroll
    for (int m = 0; m < FM; ++m)
#pragma unroll
      for (int n = 0; n < FN; ++n)
        acc[m][n] = __builtin_amdgcn_mfma_f32_16x16x32_bf16(af[m], bfr[n], acc[m][n], 0, 0, 0);

    __builtin_amdgcn_sched_barrier(0);
    __builtin_amdgcn_s_barrier();
    __builtin_amdgcn_sched_barrier(0);
    bcur = (bcur == 2) ? 0 : bcur + 1;
    bst = (bst == 2) ? 0 : bst + 1;
  }

#pragma unroll
  for (int m = 0; m < FM; ++m) {
    const long row = row0 + wm * FM * 16 + m * 16 + kgrp * 4;
#pragma unroll
    for (int n = 0; n < FN; ++n) {
      const long col = col0 + wn * FN * 16 + n * 16 + lrow;
      if (col < Nreal) {
        const float bb = bias ? bias[col] : 0.f;
        const float sc = (col < scale_ncols) ? scale : 1.f;
#pragma unroll
        for (int r = 0; r < 4; ++r) {
          const long idx = coff + (row + r) * ldc + col;
          float v = (acc[m][n][r] + bb) * sc;
          if (resid) v += resid[idx];
          if (relu) v = fmaxf(v, 0.f);
          if (outF) outF[idx] = v;
          else outB[idx] = f2bf(v);
        }
      }
    }
  }
}

extern "C" void kernel_launch(void* const* d_in, const int* in_sizes, int n_in,
                              void* d_out, int out_size, void* d_ws, size_t ws_size,
                              hipStream_t stream) {
  const int* x = (const int*)d_in[0];
  const float* tok_emb = (const float*)d_in[1];
  const float* Wq = (const float*)d_in[2];
  const float* bq = (const float*)d_in[3];
  const float* Wk = (const float*)d_in[4];
  const float* bk = (const float*)d_in[5];
  const float* Wv = (const float*)d_in[6];
  const float* bv = (const float*)d_in[7];
  const float* Wo = (const float*)d_in[8];
  const float* bo = (const float*)d_in[9];
  const float* ln1g = (const float*)d_in[10];
  const float* ln1b = (const float*)d_in[11];
  const float* ln2g = (const float*)d_in[12];
  const float* ln2b = (const float*)d_in[13];
  const float* W1 = (const float*)d_in[14];
  const float* b1 = (const float*)d_in[15];
  const float* W2 = (const float*)d_in[16];
  const float* b2 = (const float*)d_in[17];
  const float* lnfg = (const float*)d_in[18];
  const float* lnfb = (const float*)d_in[19];
  const float* Wout = (const float*)d_in[20];
  const float* bout = (const float*)d_in[21];

  char* p = (char*)d_ws;
  auto alloc = [&](size_t bytes) {
    void* r = (void*)p;
    p += (bytes + 255) & ~(size_t)255;
    return r;
  };
  float* h = (float*)alloc(2048L * 768 * 4);
  u16* y = (u16*)alloc(2048L * 768 * 2);
  u16* qkv = (u16*)alloc(2048L * 2304 * 2);
  u16* v_t = (u16*)alloc(2L * 768 * 1024 * 2);
  u16* att = (u16*)alloc(2048L * 768 * 2);
  u16* mid = (u16*)alloc(2048L * 3072 * 2);
  u16* qkv_t = (u16*)alloc(2304L * 768 * 2);
  u16* wo_t = (u16*)alloc(768L * 768 * 2);
  u16* w1_t = (u16*)alloc(768L * 3072 * 2);
  u16* w2_t = (u16*)alloc(768L * 3072 * 2);
  u16* wout_t = (u16*)alloc(50304L * 768 * 2);
  float* bqkv_all = (float*)alloc(12L * 2304 * 4);

  const dim3 tb(256);
  const dim3 cb(32, 8);

  embed_kernel<<<2048, tb, 0, stream>>>(x, tok_emb, h);
  bias_all<<<108, tb, 0, stream>>>(bq, bk, bv, bqkv_all);
  conv_transpose<<<dim3(1572, 24), cb, 0, stream>>>(Wout, wout_t, 768, 50257, 50304);

  for (int l = 0; l < 12; ++l) {
    conv_all<<<6912, cb, 0, stream>>>(
        Wq + l * 589824L, Wk + l * 589824L, Wv + l * 589824L, Wo + l * 589824L,
        W1 + l * 2359296L, W2 + l * 2359296L, qkv_t, wo_t, w1_t, w2_t);

    ln_kernel<<<2048, tb, 0, stream>>>(h, ln1g + l * 768, ln1b + l * 768, y);

    // fused QKV: qkv = (y @ [Wq|Wk|Wv] + bqkv), q columns scaled by 1/8
    gemm_bf16<64, 64, 2, 2, false><<<dim3(36, 32, 1), tb, 0, stream>>>(
        y, qkv_t, bqkv_all + l * 2304, nullptr, nullptr, qkv,
        768, 768, 768, 2304, 0, 0, 0, 0, 0, 0, 1, 2304, 0.125f, 768, 0);

    transpose_v<<<dim3(24, 32, 2), cb, 0, stream>>>(qkv, v_t);

    flash_attn<<<dim3(16, 12, 2), tb, 0, stream>>>(qkv, v_t, att);

    // h += att @ Wo + bo
    gemm_bf16<64, 64, 2, 2, false><<<dim3(12, 32, 1), tb, 0, stream>>>(
        att, wo_t, bo + l * 768, h, h, nullptr,
        768, 768, 768, 768, 0, 0, 0, 0, 0, 0, 1, 768, 1.f, 0, 0);

    ln_kernel<<<2048, tb, 0, stream>>>(h, ln2g + l * 768, ln2b + l * 768, y);

    // mid = relu(y @ W1 + b1)
    gemm_bf16<64, 64, 2, 2, false><<<dim3(48, 32, 1), tb, 0, stream>>>(
        y, w1_t, b1 + l * 3072, nullptr, nullptr, mid,
        768, 768, 768, 3072, 0, 0, 0, 0, 0, 0, 1, 3072, 1.f, 0, 1);

    // h += mid @ W2 + b2
    gemm_bf16<64, 64, 2, 2, false><<<dim3(12, 32, 1), tb, 0, stream>>>(
        mid, w2_t, b2 + l * 768, h, h, nullptr,
        3072, 3072, 3072, 768, 0, 0, 0, 0, 0, 0, 1, 768, 1.f, 0, 0);
  }

  ln_kernel<<<2048, tb, 0, stream>>>(h, lnfg, lnfb, y);

  // logits = y @ Wout + bout  (remapped 1-D grid: 393 panels x 16 row-blocks)
  gemm_bf16<128, 128, 4, 4, true><<<dim3(6288, 1, 1), tb, 0, stream>>>(
      y, wout_t, bout, nullptr, (float*)d_out, nullptr,
      768, 768, 768, 50257, 0, 0, 0, 0, 0, 0, 1, 50257, 1.f, 0, 0);
}

// Round 7
// 2214.261 us; speedup vs baseline: 2.1177x; 1.1094x over previous
//
#include <hip/hip_runtime.h>
#include <hip/hip_bf16.h>
#include <stdint.h>

typedef __attribute__((ext_vector_type(8))) short bf16x8;
typedef __attribute__((ext_vector_type(4))) float f32x4;
typedef unsigned short u16;
typedef unsigned int u32;

__device__ inline float bf2f(u16 u) {
  unsigned int x = ((unsigned int)u) << 16;
  return __builtin_bit_cast(float, x);
}
__device__ inline u16 f2bf(float f) {
  unsigned int x = __builtin_bit_cast(unsigned int, f);
  unsigned int r = x + 0x7fffu + ((x >> 16) & 1u);
  return (u16)(r >> 16);
}

__device__ inline void load_lds16(const void* g, void* l) {
  __builtin_amdgcn_global_load_lds(
      (const __attribute__((address_space(1))) unsigned int*)g,
      (__attribute__((address_space(3))) unsigned int*)l, 16, 0, 0);
}

template <int N>
__device__ inline void waitv() {
  if constexpr (N == 0) asm volatile("s_waitcnt vmcnt(0)" ::: "memory");
  else if constexpr (N == 2) asm volatile("s_waitcnt vmcnt(2)" ::: "memory");
  else if constexpr (N == 4) asm volatile("s_waitcnt vmcnt(4)" ::: "memory");
  else if constexpr (N == 8) asm volatile("s_waitcnt vmcnt(8)" ::: "memory");
}

// swizzled byte offset within a tile of 128-byte rows
#define SWB(r, cb) (((r) << 7) + ((cb) ^ (((r) & 7) << 4)))

// ---------------- embedding + positional encoding ----------------
__global__ __launch_bounds__(256) void embed_kernel(
    const int* __restrict__ x, const float* __restrict__ emb,
    float* __restrict__ h) {
  const int row = blockIdx.x;          // b*1024 + s
  const int s = row & 1023;
  const int tok = x[row];
  const int tid = threadIdx.x;
  const float c = -logf(10000.f) / 768.f;
#pragma unroll
  for (int i = 0; i < 3; ++i) {
    const int d = tid + i * 256;
    const int deven = d & ~1;
    const float ang = (float)s * expf((float)deven * c);
    const float pe = (d & 1) ? cosf(ang) : sinf(ang);
    h[(long)row * 768 + d] = emb[(long)tok * 768 + d] * 27.712812921102035f + pe;
  }
}

// ---------------- layernorm (f32 in -> bf16 out) ----------------
__global__ __launch_bounds__(256) void ln_kernel(
    const float* __restrict__ X, const float* __restrict__ g,
    const float* __restrict__ b, u16* __restrict__ Y) {
  const int row = blockIdx.x;
  const float* xr = X + (long)row * 768;
  const int tid = threadIdx.x;
  float v[3];
  float s = 0.f, sq = 0.f;
#pragma unroll
  for (int i = 0; i < 3; ++i) {
    v[i] = xr[tid + i * 256];
    s += v[i];
    sq += v[i] * v[i];
  }
  __shared__ float red[8];
#pragma unroll
  for (int off = 32; off > 0; off >>= 1) {
    s += __shfl_down(s, off);
    sq += __shfl_down(sq, off);
  }
  const int lane = tid & 63, wid = tid >> 6;
  if (lane == 0) { red[wid] = s; red[wid + 4] = sq; }
  __syncthreads();
  s = red[0] + red[1] + red[2] + red[3];
  sq = red[4] + red[5] + red[6] + red[7];
  const float mean = s * (1.f / 768.f);
  const float var = sq * (1.f / 768.f) - mean * mean;
  const float rs = rsqrtf(var + 1e-5f);
  u16* yr = Y + (long)row * 768;
#pragma unroll
  for (int i = 0; i < 3; ++i) {
    const int d = tid + i * 256;
    yr[d] = f2bf((v[i] - mean) * rs * g[d] + b[d]);
  }
}

// ---------------- f32 (K x N) -> bf16 transposed (Npad x K) ----------------
__global__ void conv_transpose(const float* __restrict__ W, u16* __restrict__ Wt,
                               int K, int N, int Npad) {
  __shared__ float tile[32][33];
  const int n0 = blockIdx.x * 32, k0 = blockIdx.y * 32;
  const int tx = threadIdx.x, ty = threadIdx.y;
  for (int i = ty; i < 32; i += 8) {
    const int n = n0 + tx;
    tile[i][tx] = (n < N) ? W[(long)(k0 + i) * N + n] : 0.f;
  }
  __syncthreads();
  for (int i = ty; i < 32; i += 8) {
    const int n = n0 + i;
    if (n < Npad) Wt[(long)n * K + k0 + tx] = f2bf(tile[tx][i]);
  }
}

// ---- merged per-layer weight conversion: qkvo (4x 768x768) + W1 + W2 ----
__global__ void conv_all(const float* __restrict__ Wq, const float* __restrict__ Wk,
                         const float* __restrict__ Wv, const float* __restrict__ Wo,
                         const float* __restrict__ W1, const float* __restrict__ W2,
                         u16* __restrict__ qkv_t, u16* __restrict__ wo_t,
                         u16* __restrict__ w1_t, u16* __restrict__ w2_t) {
  __shared__ float tile[32][33];
  const int f = blockIdx.x;
  const float* W;
  u16* dst;
  int n0, k0, ldN, ldK;
  if (f < 2304) {
    const int z = f / 576, rem = f % 576;
    W = (z == 0) ? Wq : (z == 1) ? Wk : (z == 2) ? Wv : Wo;
    dst = (z < 3) ? qkv_t + (long)z * 768 * 768 : wo_t;
    n0 = (rem / 24) * 32; k0 = (rem % 24) * 32; ldN = 768; ldK = 768;
  } else if (f < 4608) {
    const int rem = f - 2304;
    W = W1; dst = w1_t;
    n0 = (rem / 24) * 32; k0 = (rem % 24) * 32; ldN = 3072; ldK = 768;
  } else {
    const int rem = f - 4608;
    W = W2; dst = w2_t;
    n0 = (rem / 96) * 32; k0 = (rem % 96) * 32; ldN = 768; ldK = 3072;
  }
  const int tx = threadIdx.x, ty = threadIdx.y;
  for (int i = ty; i < 32; i += 8)
    tile[i][tx] = W[(long)(k0 + i) * ldN + n0 + tx];
  __syncthreads();
  for (int i = ty; i < 32; i += 8)
    dst[(long)(n0 + i) * ldK + k0 + tx] = f2bf(tile[tx][i]);
}

// ---- all-layer bias concat: bqkv_all[l][2304] = [bq_l, bk_l, bv_l] ----
__global__ __launch_bounds__(256) void bias_all(
    const float* __restrict__ bq, const float* __restrict__ bk,
    const float* __restrict__ bv, float* __restrict__ o) {
  const int idx = blockIdx.x * 256 + threadIdx.x;
  const int l = idx / 2304, r = idx % 2304;
  o[idx] = (r < 768) ? bq[l * 768 + r]
         : (r < 1536) ? bk[l * 768 + r - 768] : bv[l * 768 + r - 1536];
}

// ---- v segment of qkv [2048][2304] -> v_t [2][768][1024] ----
__global__ void transpose_v(const u16* __restrict__ qkv, u16* __restrict__ v_t) {
  __shared__ u16 tile[32][33];
  const int b = blockIdx.z;
  const int c0 = blockIdx.x * 32;
  const int r0 = blockIdx.y * 32;
  const int tx = threadIdx.x, ty = threadIdx.y;
  const u16* in = qkv + (long)b * 1024 * 2304 + 1536;
  for (int i = ty; i < 32; i += 8)
    tile[i][tx] = in[(long)(r0 + i) * 2304 + c0 + tx];
  __syncthreads();
  u16* out = v_t + (long)b * 768 * 1024;
  for (int i = ty; i < 32; i += 8)
    out[(long)(c0 + i) * 1024 + r0 + tx] = tile[tx][i];
}

// ---------------- flash attention (dbuf K/V, causal tile skip) ----------------
__global__ __launch_bounds__(256) void flash_attn(
    const u16* __restrict__ qkv, const u16* __restrict__ v_t,
    u16* __restrict__ att) {
  __shared__ u16 Qs[4096];      // 8192 B: 64 rows x 128 B, swizzled
  __shared__ u16 Ks[2][4096];
  __shared__ u16 Vs[2][4096];
  __shared__ u16 Ps[4096];

  const int qt = blockIdx.x, hh = blockIdx.y, b = blockIdx.z;
  const int tid = threadIdx.x, lane = tid & 63, w = tid >> 6;
  const int q = lane & 15, g = lane >> 4;
  const int q0 = qt * 64;
  const int kt0 = (qt < 15) ? qt : 0;

  auto stageKV = [&](int buf, int kt) {
#pragma unroll
    for (int c = 0; c < 2; ++c) {
      const int o = c * 4096 + tid * 16;
      const int r = o >> 7, cb = o & 127;
      const int cbs = cb ^ ((r & 7) << 4);
      load_lds16(qkv + ((long)(b * 1024 + kt * 64 + r)) * 2304 + 768 + hh * 64 + (cbs >> 1),
                 (char*)Ks[buf] + o);
      load_lds16(v_t + ((long)(b * 768 + hh * 64 + r)) * 1024 + kt * 64 + (cbs >> 1),
                 (char*)Vs[buf] + o);
    }
  };

#pragma unroll
  for (int c = 0; c < 2; ++c) {
    const int o = c * 4096 + tid * 16;
    const int r = o >> 7, cb = o & 127;
    const int cbs = cb ^ ((r & 7) << 4);
    load_lds16(qkv + ((long)(b * 1024 + q0 + r)) * 2304 + hh * 64 + (cbs >> 1),
               (char*)Qs + o);
  }
  stageKV(0, kt0);
  waitv<4>();
  __builtin_amdgcn_sched_barrier(0);
  __builtin_amdgcn_s_barrier();
  __builtin_amdgcn_sched_barrier(0);

  bf16x8 qf[2];
#pragma unroll
  for (int c = 0; c < 2; ++c)
    qf[c] = *(const bf16x8*)((char*)Qs + SWB(w * 16 + q, c * 64 + g * 16));

  const int i_lane = q0 + w * 16 + q;
  float m = -1e30f, l = 0.f;
  f32x4 out[4];
#pragma unroll
  for (int t = 0; t < 4; ++t) out[t] = (f32x4){0.f, 0.f, 0.f, 0.f};
  u16* Pw = Ps + w * 1024;

  int cur = 0;
  for (int kt = kt0; kt < 16; ++kt) {
    if (kt + 1 < 16) { stageKV(cur ^ 1, kt + 1); waitv<4>(); }
    else waitv<0>();
    __builtin_amdgcn_sched_barrier(0);
    __builtin_amdgcn_s_barrier();
    __builtin_amdgcn_sched_barrier(0);

    f32x4 acc[4];
#pragma unroll
    for (int t = 0; t < 4; ++t) acc[t] = (f32x4){0.f, 0.f, 0.f, 0.f};
#pragma unroll
    for (int c = 0; c < 2; ++c) {
      const bf16x8 qq = qf[c];
#pragma unroll
      for (int t = 0; t < 4; ++t) {
        const bf16x8 kf = *(const bf16x8*)((char*)Ks[cur] + SWB(t * 16 + q, c * 64 + g * 16));
        acc[t] = __builtin_amdgcn_mfma_f32_16x16x32_bf16(kf, qq, acc[t], 0, 0, 0);
      }
    }

    float s[4][4];
    float tmax = -1e30f;
#pragma unroll
    for (int t = 0; t < 4; ++t)
#pragma unroll
      for (int r = 0; r < 4; ++r) {
        const int j = kt * 64 + t * 16 + g * 4 + r;
        const float v = (j <= i_lane) ? -1e9f : acc[t][r];
        s[t][r] = v;
        tmax = fmaxf(tmax, v);
      }
    tmax = fmaxf(tmax, __shfl_xor(tmax, 16));
    tmax = fmaxf(tmax, __shfl_xor(tmax, 32));
    const float mn = fmaxf(m, tmax);
    const float sf = __expf(m - mn);
    m = mn;
    float rs = 0.f;
    u16 pb[4][4];
#pragma unroll
    for (int t = 0; t < 4; ++t)
#pragma unroll
      for (int r = 0; r < 4; ++r) {
        const float pv = __expf(s[t][r] - mn);
        rs += pv;
        pb[t][r] = f2bf(pv);
      }
    rs += __shfl_xor(rs, 16);
    rs += __shfl_xor(rs, 32);
    l = l * sf + rs;
#pragma unroll
    for (int t = 0; t < 4; ++t)
#pragma unroll
      for (int r = 0; r < 4; ++r) out[t][r] *= sf;

#pragma unroll
    for (int t = 0; t < 4; ++t) {
      uint2 pk;
      pk.x = (u32)pb[t][0] | ((u32)pb[t][1] << 16);
      pk.y = (u32)pb[t][2] | ((u32)pb[t][3] << 16);
      *(uint2*)((char*)Pw + SWB(q, t * 32 + g * 8)) = pk;
    }

#pragma unroll
    for (int c = 0; c < 2; ++c) {
      const bf16x8 pf = *(const bf16x8*)((char*)Pw + SWB(q, c * 64 + g * 16));
#pragma unroll
      for (int t = 0; t < 4; ++t) {
        const bf16x8 vf = *(const bf16x8*)((char*)Vs[cur] + SWB(t * 16 + q, c * 64 + g * 16));
        out[t] = __builtin_amdgcn_mfma_f32_16x16x32_bf16(vf, pf, out[t], 0, 0, 0);
      }
    }
    __builtin_amdgcn_sched_barrier(0);
    __builtin_amdgcn_s_barrier();
    __builtin_amdgcn_sched_barrier(0);
    cur ^= 1;
  }

  const float inv = 1.f / l;
  u16* arow = att + ((long)(b * 1024 + q0 + w * 16 + q)) * 768 + hh * 64;
#pragma unroll
  for (int t = 0; t < 4; ++t) {
    uint2 pk;
    pk.x = (u32)f2bf(out[t][0] * inv) | ((u32)f2bf(out[t][1] * inv) << 16);
    pk.y = (u32)f2bf(out[t][2] * inv) | ((u32)f2bf(out[t][3] * inv) << 16);
    *(uint2*)(arow + t * 16 + g * 4) = pk;
  }
}

// ---------------- bf16 MFMA GEMM: BK=64, swizzled LDS, depth-2 counted vmcnt ----
// TH=512: 256x256 tile, 8 waves (2x4).  TH=256: 2x2 waves.
// REMAP (vocab): groups of 128 blocks = PN panels x RB row-blocks; a panel's
// row-blocks land stride-PN apart (PN multiple of 8 -> same XCD).
template <int BM, int BN, int TH, bool REMAP, int PN, int RB>
__global__ __launch_bounds__(TH, 2) void gemm_bf16(
    const u16* __restrict__ A, const u16* __restrict__ Wt,
    const float* __restrict__ bias, const float* resid,
    float* outF, u16* outB,
    int K, int lda, int ldw, int ldc,
    int Nreal, float scale, int scale_ncols, int relu) {
  constexpr int WN = (TH == 512) ? 4 : 2;
  constexpr int FM = BM / (2 * 16);          // WM = 2 always
  constexpr int FN = BN / (WN * 16);
  constexpr int ACALLS = (BM * 128) / (TH * 16);
  constexpr int BCALLS = (BN * 128) / (TH * 16);
  constexpr int LD = ACALLS + BCALLS;

  __shared__ u16 As[2][BM * 64];
  __shared__ u16 Bs[2][BN * 64];

  const int tid = threadIdx.x;
  const int lane = tid & 63;
  const int wid = tid >> 6;
  const int wm = wid / WN, wn = wid % WN;
  const int lrow = lane & 15, kgrp = lane >> 4;

  long row0, col0;
  if (REMAP) {
    const int flat = blockIdx.x;
    const int g = flat >> 7, rem = flat & 127;
    const int fullg = gridDim.x >> 7;
    int panel, rb;
    if (g < fullg) { panel = g * PN + (rem % PN); rb = rem / PN; }
    else           { panel = fullg * PN + rem / RB; rb = rem % RB; }
    row0 = (long)rb * BM;
    col0 = (long)panel * BN;
  } else {
    row0 = (long)blockIdx.y * BM;
    col0 = (long)blockIdx.x * BN;
  }

  f32x4 acc[FM][FN];
#pragma unroll
  for (int m = 0; m < FM; ++m)
#pragma unroll
    for (int n = 0; n < FN; ++n) acc[m][n] = (f32x4){0.f, 0.f, 0.f, 0.f};

  auto stage = [&](int buf, int k0) {
#pragma unroll
    for (int c = 0; c < ACALLS; ++c) {
      const int o = c * (TH * 16) + tid * 16;
      const int r = o >> 7, cb = o & 127;
      const int cbs = cb ^ ((r & 7) << 4);
      load_lds16(A + (row0 + r) * lda + k0 + (cbs >> 1), (char*)As[buf] + o);
    }
#pragma unroll
    for (int c = 0; c < BCALLS; ++c) {
      const int o = c * (TH * 16) + tid * 16;
      const int r = o >> 7, cb = o & 127;
      const int cbs = cb ^ ((r & 7) << 4);
      load_lds16(Wt + (col0 + r) * ldw + k0 + (cbs >> 1), (char*)Bs[buf] + o);
    }
  };

  const int T = K >> 6;
  stage(0, 0);
  int cur = 0;
  for (int t = 0; t < T; ++t) {
    if (t + 1 < T) { stage(cur ^ 1, (t + 1) << 6); waitv<LD>(); }
    else waitv<0>();
    __builtin_amdgcn_sched_barrier(0);
    __builtin_amdgcn_s_barrier();
    __builtin_amdgcn_sched_barrier(0);

#pragma unroll
    for (int kk = 0; kk < 2; ++kk) {
      bf16x8 af[FM], bfr[FN];
#pragma unroll
      for (int m = 0; m < FM; ++m)
        af[m] = *(const bf16x8*)((char*)As[cur] +
                 SWB(wm * FM * 16 + m * 16 + lrow, kk * 64 + kgrp * 16));
#pragma unroll
      for (int n = 0; n < FN; ++n)
        bfr[n] = *(const bf16x8*)((char*)Bs[cur] +
                 SWB(wn * FN * 16 + n * 16 + lrow, kk * 64 + kgrp * 16));
#pragma unroll
      for (int m = 0; m < FM; ++m)
#pragma unroll
        for (int n = 0; n < FN; ++n)
          acc[m][n] = __builtin_amdgcn_mfma_f32_16x16x32_bf16(af[m], bfr[n], acc[m][n], 0, 0, 0);
    }

    __builtin_amdgcn_sched_barrier(0);
    __builtin_amdgcn_s_barrier();
    __builtin_amdgcn_sched_barrier(0);
    cur ^= 1;
  }

#pragma unroll
  for (int m = 0; m < FM; ++m) {
    const long row = row0 + wm * FM * 16 + m * 16 + kgrp * 4;
#pragma unroll
    for (int n = 0; n < FN; ++n) {
      const long col = col0 + wn * FN * 16 + n * 16 + lrow;
      if (col < Nreal) {
        const float bb = bias ? bias[col] : 0.f;
        const float sc = (col < scale_ncols) ? scale : 1.f;
#pragma unroll
        for (int r = 0; r < 4; ++r) {
          const long idx = (row + r) * ldc + col;
          float v = (acc[m][n][r] + bb) * sc;
          if (resid) v += resid[idx];
          if (relu) v = fmaxf(v, 0.f);
          if (outF) outF[idx] = v;
          else outB[idx] = f2bf(v);
        }
      }
    }
  }
}

extern "C" void kernel_launch(void* const* d_in, const int* in_sizes, int n_in,
                              void* d_out, int out_size, void* d_ws, size_t ws_size,
                              hipStream_t stream) {
  const int* x = (const int*)d_in[0];
  const float* tok_emb = (const float*)d_in[1];
  const float* Wq = (const float*)d_in[2];
  const float* bq = (const float*)d_in[3];
  const float* Wk = (const float*)d_in[4];
  const float* bk = (const float*)d_in[5];
  const float* Wv = (const float*)d_in[6];
  const float* bv = (const float*)d_in[7];
  const float* Wo = (const float*)d_in[8];
  const float* bo = (const float*)d_in[9];
  const float* ln1g = (const float*)d_in[10];
  const float* ln1b = (const float*)d_in[11];
  const float* ln2g = (const float*)d_in[12];
  const float* ln2b = (const float*)d_in[13];
  const float* W1 = (const float*)d_in[14];
  const float* b1 = (const float*)d_in[15];
  const float* W2 = (const float*)d_in[16];
  const float* b2 = (const float*)d_in[17];
  const float* lnfg = (const float*)d_in[18];
  const float* lnfb = (const float*)d_in[19];
  const float* Wout = (const float*)d_in[20];
  const float* bout = (const float*)d_in[21];

  char* p = (char*)d_ws;
  auto alloc = [&](size_t bytes) {
    void* r = (void*)p;
    p += (bytes + 255) & ~(size_t)255;
    return r;
  };
  float* h = (float*)alloc(2048L * 768 * 4);
  u16* y = (u16*)alloc(2048L * 768 * 2);
  u16* qkv = (u16*)alloc(2048L * 2304 * 2);
  u16* v_t = (u16*)alloc(2L * 768 * 1024 * 2);
  u16* att = (u16*)alloc(2048L * 768 * 2);
  u16* mid = (u16*)alloc(2048L * 3072 * 2);
  u16* qkv_t = (u16*)alloc(2304L * 768 * 2);
  u16* wo_t = (u16*)alloc(768L * 768 * 2);
  u16* w1_t = (u16*)alloc(768L * 3072 * 2);
  u16* w2_t = (u16*)alloc(768L * 3072 * 2);
  u16* wout_t = (u16*)alloc(50432L * 768 * 2);
  float* bqkv_all = (float*)alloc(12L * 2304 * 4);

  const dim3 tb(256);
  const dim3 cb(32, 8);

  embed_kernel<<<2048, tb, 0, stream>>>(x, tok_emb, h);
  bias_all<<<108, tb, 0, stream>>>(bq, bk, bv, bqkv_all);
  conv_transpose<<<dim3(1576, 24), cb, 0, stream>>>(Wout, wout_t, 768, 50257, 50432);

  for (int l = 0; l < 12; ++l) {
    conv_all<<<6912, cb, 0, stream>>>(
        Wq + l * 589824L, Wk + l * 589824L, Wv + l * 589824L, Wo + l * 589824L,
        W1 + l * 2359296L, W2 + l * 2359296L, qkv_t, wo_t, w1_t, w2_t);

    ln_kernel<<<2048, tb, 0, stream>>>(h, ln1g + l * 768, ln1b + l * 768, y);

    // fused QKV: qkv = (y @ [Wq|Wk|Wv] + bqkv), q columns scaled by 1/8
    gemm_bf16<64, 64, 256, false, 0, 0><<<dim3(36, 32), tb, 0, stream>>>(
        y, qkv_t, bqkv_all + l * 2304, nullptr, nullptr, qkv,
        768, 768, 768, 2304, 2304, 0.125f, 768, 0);

    transpose_v<<<dim3(24, 32, 2), cb, 0, stream>>>(qkv, v_t);

    flash_attn<<<dim3(16, 12, 2), tb, 0, stream>>>(qkv, v_t, att);

    // h += att @ Wo + bo
    gemm_bf16<64, 64, 256, false, 0, 0><<<dim3(12, 32), tb, 0, stream>>>(
        att, wo_t, bo + l * 768, h, h, nullptr,
        768, 768, 768, 768, 768, 1.f, 0, 0);

    ln_kernel<<<2048, tb, 0, stream>>>(h, ln2g + l * 768, ln2b + l * 768, y);

    // mid = relu(y @ W1 + b1)
    gemm_bf16<64, 64, 256, false, 0, 0><<<dim3(48, 32), tb, 0, stream>>>(
        y, w1_t, b1 + l * 3072, nullptr, nullptr, mid,
        768, 768, 768, 3072, 3072, 1.f, 0, 1);

    // h += mid @ W2 + b2
    gemm_bf16<64, 64, 256, false, 0, 0><<<dim3(12, 32), tb, 0, stream>>>(
        mid, w2_t, b2 + l * 768, h, h, nullptr,
        3072, 3072, 3072, 768, 768, 1.f, 0, 0);
  }

  ln_kernel<<<2048, tb, 0, stream>>>(h, lnfg, lnfb, y);

  // logits = y @ Wout + bout — 256x256 tile, 512 threads, REMAP 16 panels x 8 rbs
  // NOTE: output stride (ldc) MUST be 50257 — d_out is dense (2048, 50257).
  gemm_bf16<256, 256, 512, true, 16, 8><<<dim3(1576), dim3(512), 0, stream>>>(
      y, wout_t, bout, nullptr, (float*)d_out, nullptr,
      768, 768, 768, 50257, 50257, 1.f, 0, 0);
}